// Round 2
// baseline (95196.423 us; speedup 1.0000x reference)
//
#include <hip/hip_runtime.h>
#include <stdint.h>

#define NN 50000
#define NE 200000
#define NFEAT 512
#define NHID 256
#define SEG 262144  /* 2^18 >= NE, padded bitonic segment */

typedef unsigned long long u64;
typedef unsigned int u32;

// order-preserving float -> u32 (strictly monotone), exact round-trip
__device__ __forceinline__ u32 encf(float x) {
  u32 u = __float_as_uint(x);
  return (u & 0x80000000u) ? ~u : (u | 0x80000000u);
}
__device__ __forceinline__ float decf(u32 y) {
  u32 u = (y & 0x80000000u) ? (y ^ 0x80000000u) : ~y;
  return __uint_as_float(u);
}

// LDS column swizzle for W1 tile: xor bits[4:2] with bits[7:5] (bijective,
// float4-aligned preserved) -> spreads stride-64B column reads across bank quads
#define SWZ(c) ((c) ^ ((((c) >> 5) & 7) << 2))

// ---------------- filt = relu(X@W1 + b1) @ W2 + b2  -> (NN x 4) f32 ----------------
__global__ __launch_bounds__(256) void mlp_kernel(
    const float* __restrict__ X, const float* __restrict__ W1,
    const float* __restrict__ b1, const float* __restrict__ W2,
    const float* __restrict__ b2, float* __restrict__ filt)
{
  __shared__ float As[64][33];    // +1 pad: conflict-free row reads
  __shared__ float Ws[32][256];   // swizzled columns
  __shared__ float W2s[256][4];

  const int tid = threadIdx.x;
  const int row0 = blockIdx.x * 64;
  const int tr = tid >> 4, tc = tid & 15;  // 16x16 threads; 4 rows x 16 cols each

  for (int i = tid; i < NHID * 4; i += 256) W2s[i >> 2][i & 3] = W2[i];

  float4 acc[4][4];
  #pragma unroll
  for (int i = 0; i < 4; i++)
    #pragma unroll
    for (int q = 0; q < 4; q++) acc[i][q] = make_float4(0.f, 0.f, 0.f, 0.f);

  for (int k0 = 0; k0 < NFEAT; k0 += 32) {
    __syncthreads();
    {
      const int r = tid >> 3, c4 = (tid & 7) << 2;
      #pragma unroll
      for (int rr = 0; rr < 2; rr++) {
        const int row = r + rr * 32;
        const int grow = row0 + row;
        float4 v = make_float4(0.f, 0.f, 0.f, 0.f);
        if (grow < NN) v = *(const float4*)&X[(size_t)grow * NFEAT + k0 + c4];
        As[row][c4 + 0] = v.x; As[row][c4 + 1] = v.y;
        As[row][c4 + 2] = v.z; As[row][c4 + 3] = v.w;
      }
      const int wr = tid >> 6, wc4 = (tid & 63) << 2;
      const int pc = SWZ(wc4);
      #pragma unroll
      for (int rr = 0; rr < 8; rr++) {
        const int rowk = wr + rr * 4;
        float4 v = *(const float4*)&W1[(size_t)(k0 + rowk) * NHID + wc4];
        *(float4*)&Ws[rowk][pc] = v;
      }
    }
    __syncthreads();
    #pragma unroll 8
    for (int kk = 0; kk < 32; kk++) {
      const float a0 = As[tr * 4 + 0][kk], a1 = As[tr * 4 + 1][kk],
                  a2 = As[tr * 4 + 2][kk], a3 = As[tr * 4 + 3][kk];
      #pragma unroll
      for (int q = 0; q < 4; q++) {
        const int col = tc * 16 + q * 4;
        const float4 wv = *(const float4*)&Ws[kk][SWZ(col)];
        acc[0][q].x += a0 * wv.x; acc[0][q].y += a0 * wv.y;
        acc[0][q].z += a0 * wv.z; acc[0][q].w += a0 * wv.w;
        acc[1][q].x += a1 * wv.x; acc[1][q].y += a1 * wv.y;
        acc[1][q].z += a1 * wv.z; acc[1][q].w += a1 * wv.w;
        acc[2][q].x += a2 * wv.x; acc[2][q].y += a2 * wv.y;
        acc[2][q].z += a2 * wv.z; acc[2][q].w += a2 * wv.w;
        acc[3][q].x += a3 * wv.x; acc[3][q].y += a3 * wv.y;
        acc[3][q].z += a3 * wv.z; acc[3][q].w += a3 * wv.w;
      }
    }
  }

  // epilogue: +b1, relu, partial @W2 per thread, then reduce over the 16 tc lanes
  float p[4][4];
  #pragma unroll
  for (int i = 0; i < 4; i++)
    #pragma unroll
    for (int f = 0; f < 4; f++) p[i][f] = 0.f;

  #pragma unroll
  for (int q = 0; q < 4; q++) {
    const int colb = tc * 16 + q * 4;
    float bb[4];
    #pragma unroll
    for (int j = 0; j < 4; j++) bb[j] = b1[colb + j];
    #pragma unroll
    for (int i = 0; i < 4; i++) {
      float h[4] = {acc[i][q].x + bb[0], acc[i][q].y + bb[1],
                    acc[i][q].z + bb[2], acc[i][q].w + bb[3]};
      #pragma unroll
      for (int j = 0; j < 4; j++) {
        const float hh = fmaxf(h[j], 0.f);
        #pragma unroll
        for (int f = 0; f < 4; f++) p[i][f] += hh * W2s[colb + j][f];
      }
    }
  }

  #pragma unroll
  for (int m = 1; m < 16; m <<= 1)
    #pragma unroll
    for (int i = 0; i < 4; i++)
      #pragma unroll
      for (int f = 0; f < 4; f++)
        p[i][f] += __shfl_xor(p[i][f], m, 64);

  if (tc == 0) {
    const float c0 = b2[0], c1 = b2[1], c2 = b2[2], c3 = b2[3];
    #pragma unroll
    for (int i = 0; i < 4; i++) {
      const int row = row0 + tr * 4 + i;
      if (row < NN) {
        float4 o = make_float4(p[i][0] + c0, p[i][1] + c1, p[i][2] + c2, p[i][3] + c3);
        *(float4*)&filt[(size_t)row * 4] = o;
      }
    }
  }
}

// ---------------- zero the 4 maxv slots (graph-capture-safe, no memset node) ----
__global__ void zero4_kernel(u32* __restrict__ maxv) {
  if (threadIdx.x < 4) maxv[threadIdx.x] = 0u;
}

// ---------------- encoded max(v) per filtration ----------------
__global__ __launch_bounds__(256) void maxv_kernel(const float* __restrict__ filt,
                                                   u32* __restrict__ maxv)
{
  __shared__ u32 lm[4];
  if (threadIdx.x < 4) lm[threadIdx.x] = 0u;
  __syncthreads();
  const int n = blockIdx.x * 256 + threadIdx.x;
  if (n < NN) {
    const float4 v = *(const float4*)&filt[(size_t)n * 4];
    atomicMax(&lm[0], encf(v.x));
    atomicMax(&lm[1], encf(v.y));
    atomicMax(&lm[2], encf(v.z));
    atomicMax(&lm[3], encf(v.w));
  }
  __syncthreads();
  if (threadIdx.x < 4) atomicMax(&maxv[threadIdx.x], lm[threadIdx.x]);
}

// ---------------- edge weights -> packed sort keys (+padding) ----------------
// NOTE: harness delivers integer inputs as int32 (NOT the reference's int64).
__global__ __launch_bounds__(256) void prep_kernel(
    const int* __restrict__ ei, const float* __restrict__ filt,
    int* __restrict__ src32, int* __restrict__ dst32, u64* __restrict__ keys)
{
  const int e = blockIdx.x * 256 + threadIdx.x;
  if (e < NE) {
    const int s = ei[e];
    const int d = ei[NE + e];
    src32[e] = s; dst32[e] = d;
    const float4 vs = *(const float4*)&filt[(size_t)s * 4];
    const float4 vd = *(const float4*)&filt[(size_t)d * 4];
    keys[0 * SEG + e] = ((u64)encf(fmaxf(vs.x, vd.x)) << 32) | (u32)e;
    keys[1 * SEG + e] = ((u64)encf(fmaxf(vs.y, vd.y)) << 32) | (u32)e;
    keys[2 * SEG + e] = ((u64)encf(fmaxf(vs.z, vd.z)) << 32) | (u32)e;
    keys[3 * SEG + e] = ((u64)encf(fmaxf(vs.w, vd.w)) << 32) | (u32)e;
  } else if (e < SEG) {
    keys[0 * SEG + e] = ~0ull; keys[1 * SEG + e] = ~0ull;
    keys[2 * SEG + e] = ~0ull; keys[3 * SEG + e] = ~0ull;
  }
}

// ---------------- UF init + output births + essential deaths ----------------
__global__ __launch_bounds__(256) void init_kernel(
    const float* __restrict__ filt, const u32* __restrict__ maxv,
    int* __restrict__ parent, int* __restrict__ usz, u64* __restrict__ mkey,
    float* __restrict__ out)
{
  const int n = blockIdx.x * 256 + threadIdx.x;
  const int f = blockIdx.y;
  if (n < NN) {
    const size_t idx = (size_t)f * NN + n;
    parent[idx] = n;
    usz[idx] = 1;
    const float v = filt[(size_t)n * 4 + f];
    mkey[idx] = ((u64)encf(v) << 32) | (u32)n;
    out[idx * 2 + 0] = v;                 // birth
    out[idx * 2 + 1] = decf(maxv[f]);     // death default = max(v) (essential)
  }
}

// ---------------- one bitonic compare-exchange pass ----------------
__global__ __launch_bounds__(256) void bitonic_kernel(u64* __restrict__ keys, int k, int j)
{
  const int i = blockIdx.x * 256 + threadIdx.x;
  u64* a = keys + (size_t)blockIdx.y * SEG;
  const int ixj = i ^ j;
  if (ixj > i) {
    const u64 x = a[i], y = a[ixj];
    const bool up = ((i & k) == 0);
    if ((x > y) == up) { a[i] = y; a[ixj] = x; }
  }
}

// ---------------- wave-filtered sequential Kruskal with elder-rule pairing ----------------
__global__ __launch_bounds__(64) void uf_kernel(
    const u64* __restrict__ keys, const int* __restrict__ src32,
    const int* __restrict__ dst32, int* parent_g, int* usz_g,
    u64* mkey_g, float* out)
{
  const int f = blockIdx.x;
  const int lane = threadIdx.x;
  int* par = parent_g + (size_t)f * NN;
  volatile int* vpar = par;
  int* sz = usz_g + (size_t)f * NN;
  u64* mk = mkey_g + (size_t)f * NN;
  const u64* ks = keys + (size_t)f * SEG;
  float* outf = out + (size_t)f * NN * 2;

  for (int base = 0; base < NE; base += 64) {  // NE % 64 == 0
    const u64 key = ks[base + lane];
    const int e = (int)(key & 0xffffffffu);
    const bool ev = ((u32)e < (u32)NE);  // defensive: padding/corrupt key -> inactive lane
    int ru = 0, rt = 0;
    if (ev) {
      const int u = src32[e], t = dst32[e];
      // read-only root find on quiescent snapshot (volatile: bypass stale caching)
      ru = u; { int p = vpar[ru]; while (p != ru) { ru = p; p = vpar[ru]; } }
      rt = t; { int p = vpar[rt]; while (p != rt) { rt = p; p = vpar[rt]; } }
    }
    // snapshot-equal roots can never merge later (connectivity is monotone)
    u64 cand = __ballot(ev && (ru != rt));
    const bool any = (cand != 0ull);
    while (cand) {
      const int l = __ffsll(cand) - 1;  // lowest lane first == sorted edge order
      cand &= (cand - 1);
      int a = __shfl(ru, l);
      int b = __shfl(rt, l);
      const u64 kl = __shfl(key, l);
      if (lane == 0) {
        // re-find with path halving (lane 0 is the only writer -> plain loads OK)
        { int p = par[a]; while (p != a) { const int g = par[p]; par[a] = g; a = g; p = par[a]; } }
        { int p = par[b]; while (p != b) { const int g = par[p]; par[b] = g; b = g; p = par[b]; } }
        if (a != b) {
          const u64 ka = mk[a], kb = mk[b];
          // younger component = larger (v, idx) min-key; its min node dies here
          const int kn = (int)(((ka > kb) ? ka : kb) & 0xffffffffu);
          outf[(size_t)kn * 2 + 1] = decf((u32)(kl >> 32));
          const int sa = sz[a], sb = sz[b];
          const int big = (sa >= sb) ? a : b;
          const int small = (sa >= sb) ? b : a;
          par[small] = big;
          sz[big] = sa + sb;
          mk[big] = (ka < kb) ? ka : kb;
        }
      }
    }
    if (any) __threadfence();  // make lane-0 writes visible to all lanes' next batch
  }
}

extern "C" void kernel_launch(void* const* d_in, const int* in_sizes, int n_in,
                              void* d_out, int out_size, void* d_ws, size_t ws_size,
                              hipStream_t stream)
{
  const float* X  = (const float*)d_in[0];
  const float* W1 = (const float*)d_in[1];
  const float* b1 = (const float*)d_in[2];
  const float* W2 = (const float*)d_in[3];
  const float* b2 = (const float*)d_in[4];
  const int*   EI = (const int*)d_in[5];   // int32 per harness contract
  float* out = (float*)d_out;

  char* w = (char*)d_ws;
  float* filt = (float*)w;  w += (size_t)NN * 4 * sizeof(float);   // 800000
  u64*  keys  = (u64*)w;    w += (size_t)4 * SEG * sizeof(u64);    // 8388608
  int*  parent= (int*)w;    w += (size_t)4 * NN * sizeof(int);     // 800000
  int*  usz   = (int*)w;    w += (size_t)4 * NN * sizeof(int);     // 800000
  u64*  mkey  = (u64*)w;    w += (size_t)4 * NN * sizeof(u64);     // 1600000
  int*  src32 = (int*)w;    w += (size_t)NE * sizeof(int);         // 800000
  int*  dst32 = (int*)w;    w += (size_t)NE * sizeof(int);         // 800000
  u32*  maxv  = (u32*)w;    w += 4 * sizeof(u32);

  const size_t need = (size_t)(w - (char*)d_ws);
  if (ws_size < need) return;  // refuse to corrupt memory; validation will fail loudly

  zero4_kernel<<<dim3(1), dim3(64), 0, stream>>>(maxv);
  mlp_kernel<<<dim3((NN + 63) / 64), dim3(256), 0, stream>>>(X, W1, b1, W2, b2, filt);
  maxv_kernel<<<dim3((NN + 255) / 256), dim3(256), 0, stream>>>(filt, maxv);
  prep_kernel<<<dim3(SEG / 256), dim3(256), 0, stream>>>(EI, filt, src32, dst32, keys);
  init_kernel<<<dim3((NN + 255) / 256, 4), dim3(256), 0, stream>>>(filt, maxv, parent, usz, mkey, out);

  for (int k = 2; k <= SEG; k <<= 1)
    for (int j = k >> 1; j >= 1; j >>= 1)
      bitonic_kernel<<<dim3(SEG / 256, 4), dim3(256), 0, stream>>>(keys, k, j);

  uf_kernel<<<dim3(4), dim3(64), 0, stream>>>(keys, src32, dst32, parent, usz, mkey, out);
}

// Round 3
// 23577.347 us; speedup vs baseline: 4.0376x; 4.0376x over previous
//
#include <hip/hip_runtime.h>
#include <stdint.h>

#define NN 50000
#define NE 200000
#define NFEAT 512
#define NHID 256
#define SEG 262144   /* 2^18 >= NE edge sort segment */
#define SEGN 65536   /* 2^16 >= NN node sort segment */

typedef unsigned long long u64;
typedef unsigned int u32;

// order-preserving float -> u32 (strictly monotone), exact round-trip
__device__ __forceinline__ u32 encf(float x) {
  u32 u = __float_as_uint(x);
  return (u & 0x80000000u) ? ~u : (u | 0x80000000u);
}
__device__ __forceinline__ float decf(u32 y) {
  u32 u = (y & 0x80000000u) ? (y ^ 0x80000000u) : ~y;
  return __uint_as_float(u);
}

#define SWZ(c) ((c) ^ ((((c) >> 5) & 7) << 2))

// ---------------- filt = relu(X@W1 + b1) @ W2 + b2  -> (NN x 4) f32 ----------------
__global__ __launch_bounds__(256) void mlp_kernel(
    const float* __restrict__ X, const float* __restrict__ W1,
    const float* __restrict__ b1, const float* __restrict__ W2,
    const float* __restrict__ b2, float* __restrict__ filt)
{
  __shared__ float As[64][33];
  __shared__ float Ws[32][256];
  __shared__ float W2s[256][4];

  const int tid = threadIdx.x;
  const int row0 = blockIdx.x * 64;
  const int tr = tid >> 4, tc = tid & 15;

  for (int i = tid; i < NHID * 4; i += 256) W2s[i >> 2][i & 3] = W2[i];

  float4 acc[4][4];
  #pragma unroll
  for (int i = 0; i < 4; i++)
    #pragma unroll
    for (int q = 0; q < 4; q++) acc[i][q] = make_float4(0.f, 0.f, 0.f, 0.f);

  for (int k0 = 0; k0 < NFEAT; k0 += 32) {
    __syncthreads();
    {
      const int r = tid >> 3, c4 = (tid & 7) << 2;
      #pragma unroll
      for (int rr = 0; rr < 2; rr++) {
        const int row = r + rr * 32;
        const int grow = row0 + row;
        float4 v = make_float4(0.f, 0.f, 0.f, 0.f);
        if (grow < NN) v = *(const float4*)&X[(size_t)grow * NFEAT + k0 + c4];
        As[row][c4 + 0] = v.x; As[row][c4 + 1] = v.y;
        As[row][c4 + 2] = v.z; As[row][c4 + 3] = v.w;
      }
      const int wr = tid >> 6, wc4 = (tid & 63) << 2;
      const int pc = SWZ(wc4);
      #pragma unroll
      for (int rr = 0; rr < 8; rr++) {
        const int rowk = wr + rr * 4;
        float4 v = *(const float4*)&W1[(size_t)(k0 + rowk) * NHID + wc4];
        *(float4*)&Ws[rowk][pc] = v;
      }
    }
    __syncthreads();
    #pragma unroll 8
    for (int kk = 0; kk < 32; kk++) {
      const float a0 = As[tr * 4 + 0][kk], a1 = As[tr * 4 + 1][kk],
                  a2 = As[tr * 4 + 2][kk], a3 = As[tr * 4 + 3][kk];
      #pragma unroll
      for (int q = 0; q < 4; q++) {
        const int col = tc * 16 + q * 4;
        const float4 wv = *(const float4*)&Ws[kk][SWZ(col)];
        acc[0][q].x += a0 * wv.x; acc[0][q].y += a0 * wv.y;
        acc[0][q].z += a0 * wv.z; acc[0][q].w += a0 * wv.w;
        acc[1][q].x += a1 * wv.x; acc[1][q].y += a1 * wv.y;
        acc[1][q].z += a1 * wv.z; acc[1][q].w += a1 * wv.w;
        acc[2][q].x += a2 * wv.x; acc[2][q].y += a2 * wv.y;
        acc[2][q].z += a2 * wv.z; acc[2][q].w += a2 * wv.w;
        acc[3][q].x += a3 * wv.x; acc[3][q].y += a3 * wv.y;
        acc[3][q].z += a3 * wv.z; acc[3][q].w += a3 * wv.w;
      }
    }
  }

  float p[4][4];
  #pragma unroll
  for (int i = 0; i < 4; i++)
    #pragma unroll
    for (int f = 0; f < 4; f++) p[i][f] = 0.f;

  #pragma unroll
  for (int q = 0; q < 4; q++) {
    const int colb = tc * 16 + q * 4;
    float bb[4];
    #pragma unroll
    for (int j = 0; j < 4; j++) bb[j] = b1[colb + j];
    #pragma unroll
    for (int i = 0; i < 4; i++) {
      float h[4] = {acc[i][q].x + bb[0], acc[i][q].y + bb[1],
                    acc[i][q].z + bb[2], acc[i][q].w + bb[3]};
      #pragma unroll
      for (int j = 0; j < 4; j++) {
        const float hh = fmaxf(h[j], 0.f);
        #pragma unroll
        for (int f = 0; f < 4; f++) p[i][f] += hh * W2s[colb + j][f];
      }
    }
  }

  #pragma unroll
  for (int m = 1; m < 16; m <<= 1)
    #pragma unroll
    for (int i = 0; i < 4; i++)
      #pragma unroll
      for (int f = 0; f < 4; f++)
        p[i][f] += __shfl_xor(p[i][f], m, 64);

  if (tc == 0) {
    const float c0 = b2[0], c1 = b2[1], c2 = b2[2], c3 = b2[3];
    #pragma unroll
    for (int i = 0; i < 4; i++) {
      const int row = row0 + tr * 4 + i;
      if (row < NN) {
        float4 o = make_float4(p[i][0] + c0, p[i][1] + c1, p[i][2] + c2, p[i][3] + c3);
        *(float4*)&filt[(size_t)row * 4] = o;
      }
    }
  }
}

__global__ void zero4_kernel(u32* __restrict__ maxv) {
  if (threadIdx.x < 4) maxv[threadIdx.x] = 0u;
}

__global__ __launch_bounds__(256) void maxv_kernel(const float* __restrict__ filt,
                                                   u32* __restrict__ maxv)
{
  __shared__ u32 lm[4];
  if (threadIdx.x < 4) lm[threadIdx.x] = 0u;
  __syncthreads();
  const int n = blockIdx.x * 256 + threadIdx.x;
  if (n < NN) {
    const float4 v = *(const float4*)&filt[(size_t)n * 4];
    atomicMax(&lm[0], encf(v.x));
    atomicMax(&lm[1], encf(v.y));
    atomicMax(&lm[2], encf(v.z));
    atomicMax(&lm[3], encf(v.w));
  }
  __syncthreads();
  if (threadIdx.x < 4) atomicMax(&maxv[threadIdx.x], lm[threadIdx.x]);
}

// ---------------- node sort keys: (enc(v), node), padded ----------------
__global__ __launch_bounds__(256) void nodeprep_kernel(const float* __restrict__ filt,
                                                       u64* __restrict__ nodekeys)
{
  const int n = blockIdx.x * 256 + threadIdx.x;
  const int f = blockIdx.y;
  if (n < NN) {
    const float v = filt[(size_t)n * 4 + f];
    nodekeys[(size_t)f * SEGN + n] = ((u64)encf(v) << 32) | (u32)n;
  } else if (n < SEGN) {
    nodekeys[(size_t)f * SEGN + n] = ~0ull;
  }
}

// ---------------- rank scatter + parent init (rank space) ----------------
__global__ __launch_bounds__(256) void rank_kernel(const u64* __restrict__ nodekeys,
                                                   u32* __restrict__ rankOf,
                                                   u32* __restrict__ nodeOf,
                                                   u32* __restrict__ parent_r)
{
  const int j = blockIdx.x * 256 + threadIdx.x;
  const int f = blockIdx.y;
  if (j < SEGN) {
    parent_r[(size_t)f * SEGN + j] = (u32)j;
    if (j < NN) {
      const u64 kk = nodekeys[(size_t)f * SEGN + j];
      const u32 node = (u32)(kk & 0xffffffffu);
      rankOf[(size_t)f * NN + node] = (u32)j;
      nodeOf[(size_t)f * SEGN + j] = node;
    }
  }
}

// ---------------- births + essential deaths ----------------
__global__ __launch_bounds__(256) void init_kernel(
    const float* __restrict__ filt, const u32* __restrict__ maxv,
    float* __restrict__ out)
{
  const int n = blockIdx.x * 256 + threadIdx.x;
  const int f = blockIdx.y;
  if (n < NN) {
    const size_t idx = (size_t)f * NN + n;
    out[idx * 2 + 0] = filt[(size_t)n * 4 + f];
    out[idx * 2 + 1] = decf(maxv[f]);
  }
}

// ---------------- edge keys + rank-space endpoints ----------------
__global__ __launch_bounds__(256) void prep_kernel(
    const int* __restrict__ ei, const float* __restrict__ filt,
    const u32* __restrict__ rankOf,
    u32* __restrict__ erank, u64* __restrict__ keys)
{
  const int e = blockIdx.x * 256 + threadIdx.x;
  if (e < NE) {
    const int s = ei[e];
    const int d = ei[NE + e];
    const float4 vs = *(const float4*)&filt[(size_t)s * 4];
    const float4 vd = *(const float4*)&filt[(size_t)d * 4];
    keys[0 * SEG + e] = ((u64)encf(fmaxf(vs.x, vd.x)) << 32) | (u32)e;
    keys[1 * SEG + e] = ((u64)encf(fmaxf(vs.y, vd.y)) << 32) | (u32)e;
    keys[2 * SEG + e] = ((u64)encf(fmaxf(vs.z, vd.z)) << 32) | (u32)e;
    keys[3 * SEG + e] = ((u64)encf(fmaxf(vs.w, vd.w)) << 32) | (u32)e;
    #pragma unroll
    for (int f = 0; f < 4; f++) {
      const u32 ru = rankOf[(size_t)f * NN + s];
      const u32 rt = rankOf[(size_t)f * NN + d];
      erank[(size_t)f * NE + e] = (ru << 16) | rt;
    }
  } else if (e < SEG) {
    keys[0 * SEG + e] = ~0ull; keys[1 * SEG + e] = ~0ull;
    keys[2 * SEG + e] = ~0ull; keys[3 * SEG + e] = ~0ull;
  }
}

// ---------------- bitonic: fused LDS phases k=2..4096 ----------------
__global__ __launch_bounds__(256) void bitonic_lds_full(u64* __restrict__ keys, int seglen)
{
  __shared__ u64 sh[4096];
  u64* a = keys + (size_t)blockIdx.y * seglen + (size_t)blockIdx.x * 4096;
  const int gbase = blockIdx.x * 4096;
  for (int i = threadIdx.x; i < 4096; i += 256) sh[i] = a[i];
  __syncthreads();
  for (int k = 2; k <= 4096; k <<= 1) {
    for (int j = k >> 1; j >= 1; j >>= 1) {
      for (int p = threadIdx.x; p < 2048; p += 256) {
        const int i = ((p & ~(j - 1)) << 1) | (p & (j - 1));
        const int ixj = i + j;
        const bool up = (((gbase + i) & k) == 0);
        const u64 x = sh[i], y = sh[ixj];
        if ((x > y) == up) { sh[i] = y; sh[ixj] = x; }
      }
      __syncthreads();
    }
  }
  for (int i = threadIdx.x; i < 4096; i += 256) a[i] = sh[i];
}

// ---------------- bitonic: fused LDS tail (fixed k, j=2048..1) ----------------
__global__ __launch_bounds__(256) void bitonic_lds_tail(u64* __restrict__ keys, int seglen, int k)
{
  __shared__ u64 sh[4096];
  u64* a = keys + (size_t)blockIdx.y * seglen + (size_t)blockIdx.x * 4096;
  const int gbase = blockIdx.x * 4096;
  for (int i = threadIdx.x; i < 4096; i += 256) sh[i] = a[i];
  __syncthreads();
  for (int j = 2048; j >= 1; j >>= 1) {
    for (int p = threadIdx.x; p < 2048; p += 256) {
      const int i = ((p & ~(j - 1)) << 1) | (p & (j - 1));
      const int ixj = i + j;
      const bool up = (((gbase + i) & k) == 0);
      const u64 x = sh[i], y = sh[ixj];
      if ((x > y) == up) { sh[i] = y; sh[ixj] = x; }
    }
    __syncthreads();
  }
  for (int i = threadIdx.x; i < 4096; i += 256) a[i] = sh[i];
}

// ---------------- bitonic: one global pass (j >= 4096) ----------------
__global__ __launch_bounds__(256) void bitonic_global(u64* __restrict__ keys, int seglen,
                                                      int k, int j)
{
  const int i = blockIdx.x * 256 + threadIdx.x;
  u64* a = keys + (size_t)blockIdx.y * seglen;
  const int ixj = i ^ j;
  if (ixj > i) {
    const u64 x = a[i], y = a[ixj];
    const bool up = ((i & k) == 0);
    if ((x > y) == up) { a[i] = y; a[ixj] = x; }
  }
}

// ---------------- rank-space Kruskal, wave-resident in-order merges ----------------
__global__ __launch_bounds__(64) void uf_kernel(
    const u64* __restrict__ keys, const u32* __restrict__ erank,
    const u32* __restrict__ nodeOf, u32* parent_r, float* __restrict__ out)
{
  const int f = blockIdx.x;
  const int lane = threadIdx.x;
  u32* par = parent_r + (size_t)f * SEGN;
  const u32* ndOf = nodeOf + (size_t)f * SEGN;
  const u64* ks = keys + (size_t)f * SEG;
  const u32* er = erank + (size_t)f * NE;
  float* outf = out + (size_t)f * NN * 2;

  for (int base = 0; base < NE; base += 64) {  // NE % 64 == 0
    const u64 key = ks[base + lane];
    const u32 e = (u32)(key & 0xffffffffu);
    int u = 0, t = 0;
    if (e < (u32)NE) {
      const u32 pr = er[e];
      u = (int)(pr >> 16); t = (int)(pr & 0xffffu);
    }
    // parallel snapshot root-find with path halving (no merges concurrent ->
    // halving writes are root-preserving and race-free in effect)
    int ru = u;
    { u32 p = par[ru]; while (p != (u32)ru) { const u32 g = par[p]; par[ru] = g; ru = (int)g; p = par[ru]; } }
    int rt = t;
    { u32 p = par[rt]; while (p != (u32)rt) { const u32 g = par[p]; par[rt] = g; rt = (int)g; p = par[rt]; } }

    u64 cand = __ballot(ru != rt);
    int mu = ru, mt = rt;
    // in-order merge resolution: registers + shuffles only (no memory on the chain)
    while (cand) {
      const int l = __ffsll((long long)cand) - 1;
      cand &= (cand - 1);
      const int a = __shfl(mu, l);
      const int b = __shfl(mt, l);
      if (a != b) {
        const int win = (a < b) ? a : b;
        const int lose = (a < b) ? b : a;
        if (lane == l) {
          par[lose] = (u32)win;                       // fire-and-forget
          const u32 node = ndOf[lose];                // rank -> original node id
          outf[(size_t)node * 2 + 1] = decf((u32)(key >> 32));
        }
        mu = (mu == lose) ? win : mu;
        mt = (mt == lose) ? win : mt;
      }
    }
    __threadfence_block();  // drain stores; single-workgroup visibility via L1
  }
}

extern "C" void kernel_launch(void* const* d_in, const int* in_sizes, int n_in,
                              void* d_out, int out_size, void* d_ws, size_t ws_size,
                              hipStream_t stream)
{
  const float* X  = (const float*)d_in[0];
  const float* W1 = (const float*)d_in[1];
  const float* b1 = (const float*)d_in[2];
  const float* W2 = (const float*)d_in[3];
  const float* b2 = (const float*)d_in[4];
  const int*   EI = (const int*)d_in[5];   // int32 per harness contract
  float* out = (float*)d_out;

  char* w = (char*)d_ws;
  float* filt    = (float*)w; w += (size_t)NN * 4 * sizeof(float);    // 0.8 MB
  u64*  keys     = (u64*)w;   w += (size_t)4 * SEG * sizeof(u64);     // 8 MB
  u64*  nodekeys = (u64*)w;   w += (size_t)4 * SEGN * sizeof(u64);    // 2 MB
  u32*  parent_r = (u32*)w;   w += (size_t)4 * SEGN * sizeof(u32);    // 1 MB
  u32*  rankOf   = (u32*)w;   w += (size_t)4 * NN * sizeof(u32);      // 0.8 MB
  u32*  nodeOf   = (u32*)w;   w += (size_t)4 * SEGN * sizeof(u32);    // 1 MB
  u32*  erank    = (u32*)w;   w += (size_t)4 * NE * sizeof(u32);      // 3.2 MB
  u32*  maxv     = (u32*)w;   w += 4 * sizeof(u32);

  const size_t need = (size_t)(w - (char*)d_ws);
  if (ws_size < need) return;

  zero4_kernel<<<dim3(1), dim3(64), 0, stream>>>(maxv);
  mlp_kernel<<<dim3((NN + 63) / 64), dim3(256), 0, stream>>>(X, W1, b1, W2, b2, filt);
  maxv_kernel<<<dim3((NN + 255) / 256), dim3(256), 0, stream>>>(filt, maxv);
  nodeprep_kernel<<<dim3(SEGN / 256, 4), dim3(256), 0, stream>>>(filt, nodekeys);

  // node sort (segments of SEGN)
  bitonic_lds_full<<<dim3(SEGN / 4096, 4), dim3(256), 0, stream>>>(nodekeys, SEGN);
  for (int k = 8192; k <= SEGN; k <<= 1) {
    for (int j = k >> 1; j >= 4096; j >>= 1)
      bitonic_global<<<dim3(SEGN / 256, 4), dim3(256), 0, stream>>>(nodekeys, SEGN, k, j);
    bitonic_lds_tail<<<dim3(SEGN / 4096, 4), dim3(256), 0, stream>>>(nodekeys, SEGN, k);
  }

  rank_kernel<<<dim3(SEGN / 256, 4), dim3(256), 0, stream>>>(nodekeys, rankOf, nodeOf, parent_r);
  init_kernel<<<dim3((NN + 255) / 256, 4), dim3(256), 0, stream>>>(filt, maxv, out);
  prep_kernel<<<dim3(SEG / 256), dim3(256), 0, stream>>>(EI, filt, rankOf, erank, keys);

  // edge sort (segments of SEG)
  bitonic_lds_full<<<dim3(SEG / 4096, 4), dim3(256), 0, stream>>>(keys, SEG);
  for (int k = 8192; k <= SEG; k <<= 1) {
    for (int j = k >> 1; j >= 4096; j >>= 1)
      bitonic_global<<<dim3(SEG / 256, 4), dim3(256), 0, stream>>>(keys, SEG, k, j);
    bitonic_lds_tail<<<dim3(SEG / 4096, 4), dim3(256), 0, stream>>>(keys, SEG, k);
  }

  uf_kernel<<<dim3(4), dim3(64), 0, stream>>>(keys, erank, nodeOf, parent_r, out);
}

// Round 4
// 21535.843 us; speedup vs baseline: 4.4204x; 1.0948x over previous
//
#include <hip/hip_runtime.h>
#include <stdint.h>

#define NN 50000
#define NE 200000
#define NFEAT 512
#define NHID 256
#define SEG 262144   /* 2^18 >= NE edge sort segment */
#define SEGN 65536   /* 2^16 >= NN node sort segment */

typedef unsigned long long u64;
typedef unsigned int u32;
typedef unsigned short u16;

// order-preserving float -> u32 (strictly monotone), exact round-trip
__device__ __forceinline__ u32 encf(float x) {
  u32 u = __float_as_uint(x);
  return (u & 0x80000000u) ? ~u : (u | 0x80000000u);
}
__device__ __forceinline__ float decf(u32 y) {
  u32 u = (y & 0x80000000u) ? (y ^ 0x80000000u) : ~y;
  return __uint_as_float(u);
}

#define SWZ(c) ((c) ^ ((((c) >> 5) & 7) << 2))

// ---------------- filt = relu(X@W1 + b1) @ W2 + b2  -> (NN x 4) f32 ----------------
__global__ __launch_bounds__(256) void mlp_kernel(
    const float* __restrict__ X, const float* __restrict__ W1,
    const float* __restrict__ b1, const float* __restrict__ W2,
    const float* __restrict__ b2, float* __restrict__ filt)
{
  __shared__ float As[64][33];
  __shared__ float Ws[32][256];
  __shared__ float W2s[256][4];

  const int tid = threadIdx.x;
  const int row0 = blockIdx.x * 64;
  const int tr = tid >> 4, tc = tid & 15;

  for (int i = tid; i < NHID * 4; i += 256) W2s[i >> 2][i & 3] = W2[i];

  float4 acc[4][4];
  #pragma unroll
  for (int i = 0; i < 4; i++)
    #pragma unroll
    for (int q = 0; q < 4; q++) acc[i][q] = make_float4(0.f, 0.f, 0.f, 0.f);

  for (int k0 = 0; k0 < NFEAT; k0 += 32) {
    __syncthreads();
    {
      const int r = tid >> 3, c4 = (tid & 7) << 2;
      #pragma unroll
      for (int rr = 0; rr < 2; rr++) {
        const int row = r + rr * 32;
        const int grow = row0 + row;
        float4 v = make_float4(0.f, 0.f, 0.f, 0.f);
        if (grow < NN) v = *(const float4*)&X[(size_t)grow * NFEAT + k0 + c4];
        As[row][c4 + 0] = v.x; As[row][c4 + 1] = v.y;
        As[row][c4 + 2] = v.z; As[row][c4 + 3] = v.w;
      }
      const int wr = tid >> 6, wc4 = (tid & 63) << 2;
      const int pc = SWZ(wc4);
      #pragma unroll
      for (int rr = 0; rr < 8; rr++) {
        const int rowk = wr + rr * 4;
        float4 v = *(const float4*)&W1[(size_t)(k0 + rowk) * NHID + wc4];
        *(float4*)&Ws[rowk][pc] = v;
      }
    }
    __syncthreads();
    #pragma unroll 8
    for (int kk = 0; kk < 32; kk++) {
      const float a0 = As[tr * 4 + 0][kk], a1 = As[tr * 4 + 1][kk],
                  a2 = As[tr * 4 + 2][kk], a3 = As[tr * 4 + 3][kk];
      #pragma unroll
      for (int q = 0; q < 4; q++) {
        const int col = tc * 16 + q * 4;
        const float4 wv = *(const float4*)&Ws[kk][SWZ(col)];
        acc[0][q].x += a0 * wv.x; acc[0][q].y += a0 * wv.y;
        acc[0][q].z += a0 * wv.z; acc[0][q].w += a0 * wv.w;
        acc[1][q].x += a1 * wv.x; acc[1][q].y += a1 * wv.y;
        acc[1][q].z += a1 * wv.z; acc[1][q].w += a1 * wv.w;
        acc[2][q].x += a2 * wv.x; acc[2][q].y += a2 * wv.y;
        acc[2][q].z += a2 * wv.z; acc[2][q].w += a2 * wv.w;
        acc[3][q].x += a3 * wv.x; acc[3][q].y += a3 * wv.y;
        acc[3][q].z += a3 * wv.z; acc[3][q].w += a3 * wv.w;
      }
    }
  }

  float p[4][4];
  #pragma unroll
  for (int i = 0; i < 4; i++)
    #pragma unroll
    for (int f = 0; f < 4; f++) p[i][f] = 0.f;

  #pragma unroll
  for (int q = 0; q < 4; q++) {
    const int colb = tc * 16 + q * 4;
    float bb[4];
    #pragma unroll
    for (int j = 0; j < 4; j++) bb[j] = b1[colb + j];
    #pragma unroll
    for (int i = 0; i < 4; i++) {
      float h[4] = {acc[i][q].x + bb[0], acc[i][q].y + bb[1],
                    acc[i][q].z + bb[2], acc[i][q].w + bb[3]};
      #pragma unroll
      for (int j = 0; j < 4; j++) {
        const float hh = fmaxf(h[j], 0.f);
        #pragma unroll
        for (int f = 0; f < 4; f++) p[i][f] += hh * W2s[colb + j][f];
      }
    }
  }

  #pragma unroll
  for (int m = 1; m < 16; m <<= 1)
    #pragma unroll
    for (int i = 0; i < 4; i++)
      #pragma unroll
      for (int f = 0; f < 4; f++)
        p[i][f] += __shfl_xor(p[i][f], m, 64);

  if (tc == 0) {
    const float c0 = b2[0], c1 = b2[1], c2 = b2[2], c3 = b2[3];
    #pragma unroll
    for (int i = 0; i < 4; i++) {
      const int row = row0 + tr * 4 + i;
      if (row < NN) {
        float4 o = make_float4(p[i][0] + c0, p[i][1] + c1, p[i][2] + c2, p[i][3] + c3);
        *(float4*)&filt[(size_t)row * 4] = o;
      }
    }
  }
}

__global__ void zero4_kernel(u32* __restrict__ maxv) {
  if (threadIdx.x < 4) maxv[threadIdx.x] = 0u;
}

__global__ __launch_bounds__(256) void maxv_kernel(const float* __restrict__ filt,
                                                   u32* __restrict__ maxv)
{
  __shared__ u32 lm[4];
  if (threadIdx.x < 4) lm[threadIdx.x] = 0u;
  __syncthreads();
  const int n = blockIdx.x * 256 + threadIdx.x;
  if (n < NN) {
    const float4 v = *(const float4*)&filt[(size_t)n * 4];
    atomicMax(&lm[0], encf(v.x));
    atomicMax(&lm[1], encf(v.y));
    atomicMax(&lm[2], encf(v.z));
    atomicMax(&lm[3], encf(v.w));
  }
  __syncthreads();
  if (threadIdx.x < 4) atomicMax(&maxv[threadIdx.x], lm[threadIdx.x]);
}

// ---------------- node sort keys: (enc(v), node), padded ----------------
__global__ __launch_bounds__(256) void nodeprep_kernel(const float* __restrict__ filt,
                                                       u64* __restrict__ nodekeys)
{
  const int n = blockIdx.x * 256 + threadIdx.x;
  const int f = blockIdx.y;
  if (n < NN) {
    const float v = filt[(size_t)n * 4 + f];
    nodekeys[(size_t)f * SEGN + n] = ((u64)encf(v) << 32) | (u32)n;
  } else if (n < SEGN) {
    nodekeys[(size_t)f * SEGN + n] = ~0ull;
  }
}

// ---------------- rank scatter ----------------
__global__ __launch_bounds__(256) void rank_kernel(const u64* __restrict__ nodekeys,
                                                   u32* __restrict__ rankOf,
                                                   u32* __restrict__ nodeOf)
{
  const int j = blockIdx.x * 256 + threadIdx.x;
  const int f = blockIdx.y;
  if (j < NN) {
    const u64 kk = nodekeys[(size_t)f * SEGN + j];
    const u32 node = (u32)(kk & 0xffffffffu);
    rankOf[(size_t)f * NN + node] = (u32)j;
    nodeOf[(size_t)f * SEGN + j] = node;
  }
}

// ---------------- births + essential deaths ----------------
__global__ __launch_bounds__(256) void init_kernel(
    const float* __restrict__ filt, const u32* __restrict__ maxv,
    float* __restrict__ out)
{
  const int n = blockIdx.x * 256 + threadIdx.x;
  const int f = blockIdx.y;
  if (n < NN) {
    const size_t idx = (size_t)f * NN + n;
    out[idx * 2 + 0] = filt[(size_t)n * 4 + f];
    out[idx * 2 + 1] = decf(maxv[f]);
  }
}

// ---------------- edge keys + rank-space endpoints ----------------
__global__ __launch_bounds__(256) void prep_kernel(
    const int* __restrict__ ei, const float* __restrict__ filt,
    const u32* __restrict__ rankOf,
    u32* __restrict__ erank, u64* __restrict__ keys)
{
  const int e = blockIdx.x * 256 + threadIdx.x;
  if (e < NE) {
    const int s = ei[e];
    const int d = ei[NE + e];
    const float4 vs = *(const float4*)&filt[(size_t)s * 4];
    const float4 vd = *(const float4*)&filt[(size_t)d * 4];
    keys[0 * SEG + e] = ((u64)encf(fmaxf(vs.x, vd.x)) << 32) | (u32)e;
    keys[1 * SEG + e] = ((u64)encf(fmaxf(vs.y, vd.y)) << 32) | (u32)e;
    keys[2 * SEG + e] = ((u64)encf(fmaxf(vs.z, vd.z)) << 32) | (u32)e;
    keys[3 * SEG + e] = ((u64)encf(fmaxf(vs.w, vd.w)) << 32) | (u32)e;
    #pragma unroll
    for (int f = 0; f < 4; f++) {
      const u32 ru = rankOf[(size_t)f * NN + s];
      const u32 rt = rankOf[(size_t)f * NN + d];
      erank[(size_t)f * NE + e] = (ru << 16) | rt;
    }
  } else if (e < SEG) {
    keys[0 * SEG + e] = ~0ull; keys[1 * SEG + e] = ~0ull;
    keys[2 * SEG + e] = ~0ull; keys[3 * SEG + e] = ~0ull;
  }
}

// ---------------- bitonic: fused LDS phases k=2..4096 ----------------
__global__ __launch_bounds__(256) void bitonic_lds_full(u64* __restrict__ keys, int seglen)
{
  __shared__ u64 sh[4096];
  u64* a = keys + (size_t)blockIdx.y * seglen + (size_t)blockIdx.x * 4096;
  const int gbase = blockIdx.x * 4096;
  for (int i = threadIdx.x; i < 4096; i += 256) sh[i] = a[i];
  __syncthreads();
  for (int k = 2; k <= 4096; k <<= 1) {
    for (int j = k >> 1; j >= 1; j >>= 1) {
      for (int p = threadIdx.x; p < 2048; p += 256) {
        const int i = ((p & ~(j - 1)) << 1) | (p & (j - 1));
        const int ixj = i + j;
        const bool up = (((gbase + i) & k) == 0);
        const u64 x = sh[i], y = sh[ixj];
        if ((x > y) == up) { sh[i] = y; sh[ixj] = x; }
      }
      __syncthreads();
    }
  }
  for (int i = threadIdx.x; i < 4096; i += 256) a[i] = sh[i];
}

// ---------------- bitonic: fused LDS tail (fixed k, j=2048..1) ----------------
__global__ __launch_bounds__(256) void bitonic_lds_tail(u64* __restrict__ keys, int seglen, int k)
{
  __shared__ u64 sh[4096];
  u64* a = keys + (size_t)blockIdx.y * seglen + (size_t)blockIdx.x * 4096;
  const int gbase = blockIdx.x * 4096;
  for (int i = threadIdx.x; i < 4096; i += 256) sh[i] = a[i];
  __syncthreads();
  for (int j = 2048; j >= 1; j >>= 1) {
    for (int p = threadIdx.x; p < 2048; p += 256) {
      const int i = ((p & ~(j - 1)) << 1) | (p & (j - 1));
      const int ixj = i + j;
      const bool up = (((gbase + i) & k) == 0);
      const u64 x = sh[i], y = sh[ixj];
      if ((x > y) == up) { sh[i] = y; sh[ixj] = x; }
    }
    __syncthreads();
  }
  for (int i = threadIdx.x; i < 4096; i += 256) a[i] = sh[i];
}

// ---------------- bitonic: one global pass (j >= 4096) ----------------
__global__ __launch_bounds__(256) void bitonic_global(u64* __restrict__ keys, int seglen,
                                                      int k, int j)
{
  const int i = blockIdx.x * 256 + threadIdx.x;
  u64* a = keys + (size_t)blockIdx.y * seglen;
  const int ixj = i ^ j;
  if (ixj > i) {
    const u64 x = a[i], y = a[ixj];
    const bool up = ((i & k) == 0);
    if ((x > y) == up) { a[i] = y; a[ixj] = x; }
  }
}

// ---------------- rank-space Kruskal: LDS u16 parent, dual finds, prefetch ----------------
__global__ __launch_bounds__(64) void uf_kernel(
    const u64* __restrict__ keys, const u32* __restrict__ erank,
    const u32* __restrict__ nodeOf, float* __restrict__ out)
{
  __shared__ u16 par[NN];   // 100 KB LDS: ranks < 50000 < 65536
  const int f = blockIdx.x;
  const int lane = threadIdx.x;
  const u32* ndOf = nodeOf + (size_t)f * SEGN;
  const u64* ks = keys + (size_t)f * SEG;
  const u32* er = erank + (size_t)f * NE;
  float* outf = out + (size_t)f * NN * 2;

  // parent = identity, packed u32 stores (NN even)
  u32* par32 = (u32*)par;
  for (int j = lane; j < NN / 2; j += 64)
    par32[j] = ((u32)(2 * j + 1) << 16) | (u32)(2 * j);
  __syncthreads();

  // prefetch batch 0
  u64 key = ks[lane];
  u32 pr;
  { const u32 e0 = (u32)(key & 0xffffffffu); pr = (e0 < (u32)NE) ? er[e0] : 0u; }

  for (int base = 0; base < NE; base += 64) {  // NE % 64 == 0
    // prefetch next batch's key early (global ~L2 latency hides under finds)
    u64 nkey = ~0ull;
    if (base + 64 < NE) nkey = ks[base + 64 + lane];

    const u32 e = (u32)(key & 0xffffffffu);
    int u = 0, t = 0;
    if (e < (u32)NE) { u = (int)(pr >> 16); t = (int)(pr & 0xffffu); }

    // dual interleaved path-halving find in LDS
    int ru = u, rt = t;
    u32 pu = par[ru], pt = par[rt];
    while (pu != (u32)ru || pt != (u32)rt) {
      const u32 gu = par[pu];          // independent dual loads issue together
      const u32 gt = par[pt];
      if (pu != (u32)ru) { par[ru] = (u16)gu; ru = (int)gu; }
      if (pt != (u32)rt) { par[rt] = (u16)gt; rt = (int)gt; }
      pu = par[ru]; pt = par[rt];
    }

    // prefetch next batch's endpoint ranks (depends on nkey; overlaps merge loop)
    u32 npr = 0u;
    if (base + 64 < NE) {
      const u32 ne = (u32)(nkey & 0xffffffffu);
      if (ne < (u32)NE) npr = er[ne];
    }

    // in-order merge resolution: registers + shuffles only
    u64 cand = __ballot(ru != rt);
    int mu = ru, mt = rt;
    while (cand) {
      const int l = __ffsll((long long)cand) - 1;
      cand &= (cand - 1);
      const int a = __shfl(mu, l);
      const int b = __shfl(mt, l);
      if (a != b) {
        const int win = (a < b) ? a : b;
        const int lose = (a < b) ? b : a;
        if (lane == l) {
          par[lose] = (u16)win;                      // root merge (LDS)
          const u32 node = ndOf[lose];               // fire-and-forget epilogue
          outf[(size_t)node * 2 + 1] = decf((u32)(key >> 32));
        }
        mu = (mu == lose) ? win : mu;
        mt = (mt == lose) ? win : mt;
      }
    }
    // commit this batch's LDS writes before next batch's reads (single wave:
    // lgkmcnt(0) suffices; avoid vmcnt drain of the out stores)
    asm volatile("s_waitcnt lgkmcnt(0)" ::: "memory");
    __builtin_amdgcn_sched_barrier(0);
    key = nkey; pr = npr;
  }
}

extern "C" void kernel_launch(void* const* d_in, const int* in_sizes, int n_in,
                              void* d_out, int out_size, void* d_ws, size_t ws_size,
                              hipStream_t stream)
{
  const float* X  = (const float*)d_in[0];
  const float* W1 = (const float*)d_in[1];
  const float* b1 = (const float*)d_in[2];
  const float* W2 = (const float*)d_in[3];
  const float* b2 = (const float*)d_in[4];
  const int*   EI = (const int*)d_in[5];   // int32 per harness contract
  float* out = (float*)d_out;

  char* w = (char*)d_ws;
  float* filt    = (float*)w; w += (size_t)NN * 4 * sizeof(float);    // 0.8 MB
  u64*  keys     = (u64*)w;   w += (size_t)4 * SEG * sizeof(u64);     // 8 MB
  u64*  nodekeys = (u64*)w;   w += (size_t)4 * SEGN * sizeof(u64);    // 2 MB
  u32*  rankOf   = (u32*)w;   w += (size_t)4 * NN * sizeof(u32);      // 0.8 MB
  u32*  nodeOf   = (u32*)w;   w += (size_t)4 * SEGN * sizeof(u32);    // 1 MB
  u32*  erank    = (u32*)w;   w += (size_t)4 * NE * sizeof(u32);      // 3.2 MB
  u32*  maxv     = (u32*)w;   w += 4 * sizeof(u32);

  const size_t need = (size_t)(w - (char*)d_ws);
  if (ws_size < need) return;

  zero4_kernel<<<dim3(1), dim3(64), 0, stream>>>(maxv);
  mlp_kernel<<<dim3((NN + 63) / 64), dim3(256), 0, stream>>>(X, W1, b1, W2, b2, filt);
  maxv_kernel<<<dim3((NN + 255) / 256), dim3(256), 0, stream>>>(filt, maxv);
  nodeprep_kernel<<<dim3(SEGN / 256, 4), dim3(256), 0, stream>>>(filt, nodekeys);

  // node sort (segments of SEGN)
  bitonic_lds_full<<<dim3(SEGN / 4096, 4), dim3(256), 0, stream>>>(nodekeys, SEGN);
  for (int k = 8192; k <= SEGN; k <<= 1) {
    for (int j = k >> 1; j >= 4096; j >>= 1)
      bitonic_global<<<dim3(SEGN / 256, 4), dim3(256), 0, stream>>>(nodekeys, SEGN, k, j);
    bitonic_lds_tail<<<dim3(SEGN / 4096, 4), dim3(256), 0, stream>>>(nodekeys, SEGN, k);
  }

  rank_kernel<<<dim3(SEGN / 256, 4), dim3(256), 0, stream>>>(nodekeys, rankOf, nodeOf);
  init_kernel<<<dim3((NN + 255) / 256, 4), dim3(256), 0, stream>>>(filt, maxv, out);
  prep_kernel<<<dim3(SEG / 256), dim3(256), 0, stream>>>(EI, filt, rankOf, erank, keys);

  // edge sort (segments of SEG)
  bitonic_lds_full<<<dim3(SEG / 4096, 4), dim3(256), 0, stream>>>(keys, SEG);
  for (int k = 8192; k <= SEG; k <<= 1) {
    for (int j = k >> 1; j >= 4096; j >>= 1)
      bitonic_global<<<dim3(SEG / 256, 4), dim3(256), 0, stream>>>(keys, SEG, k, j);
    bitonic_lds_tail<<<dim3(SEG / 4096, 4), dim3(256), 0, stream>>>(keys, SEG, k);
  }

  uf_kernel<<<dim3(4), dim3(64), 0, stream>>>(keys, erank, nodeOf, out);
}

// Round 5
// 13856.058 us; speedup vs baseline: 6.8704x; 1.5543x over previous
//
#include <hip/hip_runtime.h>
#include <stdint.h>

#define NN 50000
#define NE 200000
#define NFEAT 512
#define NHID 256
#define SEGN 65536   /* 2^16 >= NN: node-key sort + MSF-key sort segment */
#define BOR_ROUNDS 16 /* components at least halve per round: 2^16 > 50000 */

typedef unsigned long long u64;
typedef unsigned int u32;
typedef unsigned short u16;

// order-preserving float -> u32 (strictly monotone), exact round-trip
__device__ __forceinline__ u32 encf(float x) {
  u32 u = __float_as_uint(x);
  return (u & 0x80000000u) ? ~u : (u | 0x80000000u);
}
__device__ __forceinline__ float decf(u32 y) {
  u32 u = (y & 0x80000000u) ? (y ^ 0x80000000u) : ~y;
  return __uint_as_float(u);
}

#define SWZ(c) ((c) ^ ((((c) >> 5) & 7) << 2))

// ---------------- filt = relu(X@W1 + b1) @ W2 + b2  -> (NN x 4) f32 ----------------
__global__ __launch_bounds__(256) void mlp_kernel(
    const float* __restrict__ X, const float* __restrict__ W1,
    const float* __restrict__ b1, const float* __restrict__ W2,
    const float* __restrict__ b2, float* __restrict__ filt)
{
  __shared__ float As[64][33];
  __shared__ float Ws[32][256];
  __shared__ float W2s[256][4];

  const int tid = threadIdx.x;
  const int row0 = blockIdx.x * 64;
  const int tr = tid >> 4, tc = tid & 15;

  for (int i = tid; i < NHID * 4; i += 256) W2s[i >> 2][i & 3] = W2[i];

  float4 acc[4][4];
  #pragma unroll
  for (int i = 0; i < 4; i++)
    #pragma unroll
    for (int q = 0; q < 4; q++) acc[i][q] = make_float4(0.f, 0.f, 0.f, 0.f);

  for (int k0 = 0; k0 < NFEAT; k0 += 32) {
    __syncthreads();
    {
      const int r = tid >> 3, c4 = (tid & 7) << 2;
      #pragma unroll
      for (int rr = 0; rr < 2; rr++) {
        const int row = r + rr * 32;
        const int grow = row0 + row;
        float4 v = make_float4(0.f, 0.f, 0.f, 0.f);
        if (grow < NN) v = *(const float4*)&X[(size_t)grow * NFEAT + k0 + c4];
        As[row][c4 + 0] = v.x; As[row][c4 + 1] = v.y;
        As[row][c4 + 2] = v.z; As[row][c4 + 3] = v.w;
      }
      const int wr = tid >> 6, wc4 = (tid & 63) << 2;
      const int pc = SWZ(wc4);
      #pragma unroll
      for (int rr = 0; rr < 8; rr++) {
        const int rowk = wr + rr * 4;
        float4 v = *(const float4*)&W1[(size_t)(k0 + rowk) * NHID + wc4];
        *(float4*)&Ws[rowk][pc] = v;
      }
    }
    __syncthreads();
    #pragma unroll 8
    for (int kk = 0; kk < 32; kk++) {
      const float a0 = As[tr * 4 + 0][kk], a1 = As[tr * 4 + 1][kk],
                  a2 = As[tr * 4 + 2][kk], a3 = As[tr * 4 + 3][kk];
      #pragma unroll
      for (int q = 0; q < 4; q++) {
        const int col = tc * 16 + q * 4;
        const float4 wv = *(const float4*)&Ws[kk][SWZ(col)];
        acc[0][q].x += a0 * wv.x; acc[0][q].y += a0 * wv.y;
        acc[0][q].z += a0 * wv.z; acc[0][q].w += a0 * wv.w;
        acc[1][q].x += a1 * wv.x; acc[1][q].y += a1 * wv.y;
        acc[1][q].z += a1 * wv.z; acc[1][q].w += a1 * wv.w;
        acc[2][q].x += a2 * wv.x; acc[2][q].y += a2 * wv.y;
        acc[2][q].z += a2 * wv.z; acc[2][q].w += a2 * wv.w;
        acc[3][q].x += a3 * wv.x; acc[3][q].y += a3 * wv.y;
        acc[3][q].z += a3 * wv.z; acc[3][q].w += a3 * wv.w;
      }
    }
  }

  float p[4][4];
  #pragma unroll
  for (int i = 0; i < 4; i++)
    #pragma unroll
    for (int f = 0; f < 4; f++) p[i][f] = 0.f;

  #pragma unroll
  for (int q = 0; q < 4; q++) {
    const int colb = tc * 16 + q * 4;
    float bb[4];
    #pragma unroll
    for (int j = 0; j < 4; j++) bb[j] = b1[colb + j];
    #pragma unroll
    for (int i = 0; i < 4; i++) {
      float h[4] = {acc[i][q].x + bb[0], acc[i][q].y + bb[1],
                    acc[i][q].z + bb[2], acc[i][q].w + bb[3]};
      #pragma unroll
      for (int j = 0; j < 4; j++) {
        const float hh = fmaxf(h[j], 0.f);
        #pragma unroll
        for (int f = 0; f < 4; f++) p[i][f] += hh * W2s[colb + j][f];
      }
    }
  }

  #pragma unroll
  for (int m = 1; m < 16; m <<= 1)
    #pragma unroll
    for (int i = 0; i < 4; i++)
      #pragma unroll
      for (int f = 0; f < 4; f++)
        p[i][f] += __shfl_xor(p[i][f], m, 64);

  if (tc == 0) {
    const float c0 = b2[0], c1 = b2[1], c2 = b2[2], c3 = b2[3];
    #pragma unroll
    for (int i = 0; i < 4; i++) {
      const int row = row0 + tr * 4 + i;
      if (row < NN) {
        float4 o = make_float4(p[i][0] + c0, p[i][1] + c1, p[i][2] + c2, p[i][3] + c3);
        *(float4*)&filt[(size_t)row * 4] = o;
      }
    }
  }
}

// ---------------- setup: msf padding, Boruvka state, counters ----------------
__global__ __launch_bounds__(256) void setup_kernel(
    u64* __restrict__ msf, u32* __restrict__ comp, u64* __restrict__ minOut,
    u32* __restrict__ hookTo, u32* __restrict__ msfCnt, u32* __restrict__ done,
    u32* __restrict__ changed, u32* __restrict__ maxv)
{
  const int j = blockIdx.x * 256 + threadIdx.x;
  const int f = blockIdx.y;
  msf[(size_t)f * SEGN + j] = ~0ull;
  if (j < NN) {
    comp[(size_t)f * NN + j] = (u32)j;
    minOut[(size_t)f * NN + j] = ~0ull;
    hookTo[(size_t)f * NN + j] = (u32)j;
  }
  if (j == 0) {
    msfCnt[f] = 0u; done[f] = 0u; changed[f] = 0u;
    if (f == 0) { maxv[0] = 0u; maxv[1] = 0u; maxv[2] = 0u; maxv[3] = 0u; }
  }
}

__global__ __launch_bounds__(256) void maxv_kernel(const float* __restrict__ filt,
                                                   u32* __restrict__ maxv)
{
  __shared__ u32 lm[4];
  if (threadIdx.x < 4) lm[threadIdx.x] = 0u;
  __syncthreads();
  const int n = blockIdx.x * 256 + threadIdx.x;
  if (n < NN) {
    const float4 v = *(const float4*)&filt[(size_t)n * 4];
    atomicMax(&lm[0], encf(v.x));
    atomicMax(&lm[1], encf(v.y));
    atomicMax(&lm[2], encf(v.z));
    atomicMax(&lm[3], encf(v.w));
  }
  __syncthreads();
  if (threadIdx.x < 4) atomicMax(&maxv[threadIdx.x], lm[threadIdx.x]);
}

// ---------------- node sort keys: (enc(v), node), padded ----------------
__global__ __launch_bounds__(256) void nodeprep_kernel(const float* __restrict__ filt,
                                                       u64* __restrict__ nodekeys)
{
  const int n = blockIdx.x * 256 + threadIdx.x;
  const int f = blockIdx.y;
  if (n < NN) {
    const float v = filt[(size_t)n * 4 + f];
    nodekeys[(size_t)f * SEGN + n] = ((u64)encf(v) << 32) | (u32)n;
  } else if (n < SEGN) {
    nodekeys[(size_t)f * SEGN + n] = ~0ull;
  }
}

// ---------------- rank scatter ----------------
__global__ __launch_bounds__(256) void rank_kernel(const u64* __restrict__ nodekeys,
                                                   u32* __restrict__ rankOf,
                                                   u32* __restrict__ nodeOf)
{
  const int j = blockIdx.x * 256 + threadIdx.x;
  const int f = blockIdx.y;
  if (j < NN) {
    const u64 kk = nodekeys[(size_t)f * SEGN + j];
    const u32 node = (u32)(kk & 0xffffffffu);
    rankOf[(size_t)f * NN + node] = (u32)j;
    nodeOf[(size_t)f * SEGN + j] = node;
  }
}

// ---------------- births + essential deaths ----------------
__global__ __launch_bounds__(256) void init_kernel(
    const float* __restrict__ filt, const u32* __restrict__ maxv,
    float* __restrict__ out)
{
  const int n = blockIdx.x * 256 + threadIdx.x;
  const int f = blockIdx.y;
  if (n < NN) {
    const size_t idx = (size_t)f * NN + n;
    out[idx * 2 + 0] = filt[(size_t)n * 4 + f];
    out[idx * 2 + 1] = decf(maxv[f]);
  }
}

// ---------------- per-edge keys + rank-space endpoints ----------------
__global__ __launch_bounds__(256) void prep_kernel(
    const int* __restrict__ ei, const float* __restrict__ filt,
    const u32* __restrict__ rankOf,
    u32* __restrict__ erank, u64* __restrict__ ekeys)
{
  const int e = blockIdx.x * 256 + threadIdx.x;
  if (e >= NE) return;
  const int s = ei[e];
  const int d = ei[NE + e];
  const float4 vs = *(const float4*)&filt[(size_t)s * 4];
  const float4 vd = *(const float4*)&filt[(size_t)d * 4];
  ekeys[0 * (size_t)NE + e] = ((u64)encf(fmaxf(vs.x, vd.x)) << 32) | (u32)e;
  ekeys[1 * (size_t)NE + e] = ((u64)encf(fmaxf(vs.y, vd.y)) << 32) | (u32)e;
  ekeys[2 * (size_t)NE + e] = ((u64)encf(fmaxf(vs.z, vd.z)) << 32) | (u32)e;
  ekeys[3 * (size_t)NE + e] = ((u64)encf(fmaxf(vs.w, vd.w)) << 32) | (u32)e;
  #pragma unroll
  for (int f = 0; f < 4; f++) {
    const u32 ru = rankOf[(size_t)f * NN + s];
    const u32 rt = rankOf[(size_t)f * NN + d];
    erank[(size_t)f * NE + e] = (ru << 16) | rt;
  }
}

// ---------------- Boruvka round: per-edge min-outgoing-key selection ----------------
__global__ __launch_bounds__(256) void bor_edges(
    const u64* __restrict__ ekeys, const u32* __restrict__ erank,
    const u32* __restrict__ comp, u64* __restrict__ minOut,
    const u32* __restrict__ done)
{
  const int f = blockIdx.y;
  if (done[f]) return;
  const int e = blockIdx.x * 256 + threadIdx.x;
  if (e >= NE) return;
  const u32 pr = erank[(size_t)f * NE + e];
  const u32* cf = comp + (size_t)f * NN;
  u32 a = cf[pr >> 16]; a = cf[a];
  u32 b = cf[pr & 0xffffu]; b = cf[b];
  if (a != b) {
    const u64 k = ekeys[(size_t)f * NE + e];
    atomicMin(&minOut[(size_t)f * NN + a], k);
    atomicMin(&minOut[(size_t)f * NN + b], k);
  }
}

// ---------------- Boruvka round: choose hooks + record MSF edges ----------------
__global__ __launch_bounds__(256) void bor_choose(
    const u32* __restrict__ erank, const u32* __restrict__ comp,
    const u64* __restrict__ minOut, u32* __restrict__ hookTo,
    u64* __restrict__ msf, u32* __restrict__ msfCnt,
    const u32* __restrict__ done, u32* __restrict__ changed)
{
  const int f = blockIdx.y;
  if (done[f]) return;
  const int r = blockIdx.x * 256 + threadIdx.x;
  if (r >= NN) return;
  const u32* cf = comp + (size_t)f * NN;
  if (cf[r] != (u32)r) return;                       // roots only
  const u64 k = minOut[(size_t)f * NN + r];
  if (k == ~0ull) return;                            // isolated component
  const u32 e = (u32)(k & 0xffffffffu);
  const u32 pr = erank[(size_t)f * NE + e];
  u32 a = cf[pr >> 16]; a = cf[a];
  u32 b = cf[pr & 0xffffu]; b = cf[b];
  const u32 other = (a == (u32)r) ? b : a;
  // mutual-min pair: only the larger id hooks (records once); chains otherwise
  // strictly decrease in key along hooks -> acyclic
  if (minOut[(size_t)f * NN + other] == k && other > (u32)r) return;
  hookTo[(size_t)f * NN + r] = other;
  changed[f] = 1u;
  const u32 slot = atomicAdd(&msfCnt[f], 1u);
  msf[(size_t)f * SEGN + slot] = k;
}

// ---------------- Boruvka round: apply hooks (clean snapshot) + done flag ----------------
__global__ __launch_bounds__(256) void bor_apply(
    u32* __restrict__ comp, u32* __restrict__ hookTo,
    u32* __restrict__ done, u32* __restrict__ changed)
{
  const int f = blockIdx.y;
  if (done[f]) return;
  const int r = blockIdx.x * 256 + threadIdx.x;
  if (r >= NN) return;
  const u32 h = hookTo[(size_t)f * NN + r];
  if (h != (u32)r) {
    comp[(size_t)f * NN + r] = h;
    hookTo[(size_t)f * NN + r] = (u32)r;
  }
  if (r == 0) { if (changed[f] == 0u) done[f] = 1u; changed[f] = 0u; }
}

// ---------------- Boruvka round: pointer-jump full compression + minOut reset ----
__global__ __launch_bounds__(256) void bor_jump(
    u32* __restrict__ comp, u64* __restrict__ minOut, const u32* __restrict__ done)
{
  const int f = blockIdx.y;
  if (done[f]) return;
  const int x = blockIdx.x * 256 + threadIdx.x;
  if (x >= NN) return;
  u32* cf = comp + (size_t)f * NN;
  u32 p = cf[x];
  u32 g = cf[p];
  while (p != g) { p = g; g = cf[p]; }   // concurrent writes only shortcut
  cf[x] = p;
  minOut[(size_t)f * NN + x] = ~0ull;
}

// ---------------- bitonic: fused LDS phases k=2..4096 ----------------
__global__ __launch_bounds__(256) void bitonic_lds_full(u64* __restrict__ keys, int seglen)
{
  __shared__ u64 sh[4096];
  u64* a = keys + (size_t)blockIdx.y * seglen + (size_t)blockIdx.x * 4096;
  const int gbase = blockIdx.x * 4096;
  for (int i = threadIdx.x; i < 4096; i += 256) sh[i] = a[i];
  __syncthreads();
  for (int k = 2; k <= 4096; k <<= 1) {
    for (int j = k >> 1; j >= 1; j >>= 1) {
      for (int p = threadIdx.x; p < 2048; p += 256) {
        const int i = ((p & ~(j - 1)) << 1) | (p & (j - 1));
        const int ixj = i + j;
        const bool up = (((gbase + i) & k) == 0);
        const u64 x = sh[i], y = sh[ixj];
        if ((x > y) == up) { sh[i] = y; sh[ixj] = x; }
      }
      __syncthreads();
    }
  }
  for (int i = threadIdx.x; i < 4096; i += 256) a[i] = sh[i];
}

// ---------------- bitonic: fused LDS tail (fixed k, j=2048..1) ----------------
__global__ __launch_bounds__(256) void bitonic_lds_tail(u64* __restrict__ keys, int seglen, int k)
{
  __shared__ u64 sh[4096];
  u64* a = keys + (size_t)blockIdx.y * seglen + (size_t)blockIdx.x * 4096;
  const int gbase = blockIdx.x * 4096;
  for (int i = threadIdx.x; i < 4096; i += 256) sh[i] = a[i];
  __syncthreads();
  for (int j = 2048; j >= 1; j >>= 1) {
    for (int p = threadIdx.x; p < 2048; p += 256) {
      const int i = ((p & ~(j - 1)) << 1) | (p & (j - 1));
      const int ixj = i + j;
      const bool up = (((gbase + i) & k) == 0);
      const u64 x = sh[i], y = sh[ixj];
      if ((x > y) == up) { sh[i] = y; sh[ixj] = x; }
    }
    __syncthreads();
  }
  for (int i = threadIdx.x; i < 4096; i += 256) a[i] = sh[i];
}

// ---------------- bitonic: one global pass (j >= 4096) ----------------
__global__ __launch_bounds__(256) void bitonic_global(u64* __restrict__ keys, int seglen,
                                                      int k, int j)
{
  const int i = blockIdx.x * 256 + threadIdx.x;
  u64* a = keys + (size_t)blockIdx.y * seglen;
  const int ixj = i ^ j;
  if (ixj > i) {
    const u64 x = a[i], y = a[ixj];
    const bool up = ((i & k) == 0);
    if ((x > y) == up) { a[i] = y; a[ixj] = x; }
  }
}

// ---------------- rank-space Kruskal over sorted MSF edges only ----------------
__global__ __launch_bounds__(64) void uf_kernel(
    const u64* __restrict__ msf, const u32* __restrict__ msfCnt,
    const u32* __restrict__ erank, const u32* __restrict__ nodeOf,
    float* __restrict__ out)
{
  __shared__ u16 par[NN];   // 100 KB LDS: ranks < 50000 < 65536
  const int f = blockIdx.x;
  const int lane = threadIdx.x;
  const u32* ndOf = nodeOf + (size_t)f * SEGN;
  const u64* ks = msf + (size_t)f * SEGN;
  const u32* er = erank + (size_t)f * NE;
  float* outf = out + (size_t)f * NN * 2;
  const int cnt = (int)msfCnt[f];    // <= NN-1

  u32* par32 = (u32*)par;
  for (int j = lane; j < NN / 2; j += 64)
    par32[j] = ((u32)(2 * j + 1) << 16) | (u32)(2 * j);
  __syncthreads();

  u64 key = ~0ull; u32 pr = 0u;
  if (cnt > 0) {
    key = ks[lane];
    const u32 e0 = (u32)(key & 0xffffffffu);
    pr = (e0 < (u32)NE) ? er[e0] : 0u;
  }

  for (int base = 0; base < cnt; base += 64) {
    // prefetch next batch's keys early (overlaps finds)
    u64 nkey = ~0ull;
    if (base + 64 < cnt) nkey = ks[base + 64 + lane];

    const bool live = (base + lane < cnt);
    int u = 0, t = 0;
    if (live) { u = (int)(pr >> 16); t = (int)(pr & 0xffffu); }

    // dual interleaved path-halving find in LDS (snapshot before batch merges)
    int ru = u, rt = t;
    u32 pu = par[ru], pt = par[rt];
    while (pu != (u32)ru || pt != (u32)rt) {
      const u32 gu = par[pu];
      const u32 gt = par[pt];
      if (pu != (u32)ru) { par[ru] = (u16)gu; ru = (int)gu; }
      if (pt != (u32)rt) { par[rt] = (u16)gt; rt = (int)gt; }
      pu = par[ru]; pt = par[rt];
    }

    // prefetch next batch's endpoint ranks (overlaps merge loop)
    u32 npr = 0u;
    if (base + 64 < cnt) {
      const u32 ne = (u32)(nkey & 0xffffffffu);
      if (ne < (u32)NE) npr = er[ne];
    }

    // in-order merge resolution: registers + shuffles only
    u64 cand = __ballot(live && (ru != rt));
    int mu = ru, mt = rt;
    while (cand) {
      const int l = __ffsll((long long)cand) - 1;
      cand &= (cand - 1);
      const int a = __shfl(mu, l);
      const int b = __shfl(mt, l);
      if (a != b) {
        const int win = (a < b) ? a : b;
        const int lose = (a < b) ? b : a;
        if (lane == l) {
          par[lose] = (u16)win;                      // root merge (LDS)
          const u32 node = ndOf[lose];               // fire-and-forget epilogue
          outf[(size_t)node * 2 + 1] = decf((u32)(key >> 32));
        }
        mu = (mu == lose) ? win : mu;
        mt = (mt == lose) ? win : mt;
      }
    }
    asm volatile("s_waitcnt lgkmcnt(0)" ::: "memory");
    __builtin_amdgcn_sched_barrier(0);
    key = nkey; pr = npr;
  }
}

extern "C" void kernel_launch(void* const* d_in, const int* in_sizes, int n_in,
                              void* d_out, int out_size, void* d_ws, size_t ws_size,
                              hipStream_t stream)
{
  const float* X  = (const float*)d_in[0];
  const float* W1 = (const float*)d_in[1];
  const float* b1 = (const float*)d_in[2];
  const float* W2 = (const float*)d_in[3];
  const float* b2 = (const float*)d_in[4];
  const int*   EI = (const int*)d_in[5];   // int32 per harness contract
  float* out = (float*)d_out;

  char* w = (char*)d_ws;
  u64*  ekeys    = (u64*)w;   w += (size_t)4 * NE * sizeof(u64);      // 6.4 MB
  u64*  nodekeys = (u64*)w;   w += (size_t)4 * SEGN * sizeof(u64);    // 2 MB
  u64*  minOut   = (u64*)w;   w += (size_t)4 * NN * sizeof(u64);      // 1.6 MB
  u64*  msf      = (u64*)w;   w += (size_t)4 * SEGN * sizeof(u64);    // 2 MB
  float* filt    = (float*)w; w += (size_t)NN * 4 * sizeof(float);    // 0.8 MB
  u32*  rankOf   = (u32*)w;   w += (size_t)4 * NN * sizeof(u32);      // 0.8 MB
  u32*  nodeOf   = (u32*)w;   w += (size_t)4 * SEGN * sizeof(u32);    // 1 MB
  u32*  erank    = (u32*)w;   w += (size_t)4 * NE * sizeof(u32);      // 3.2 MB
  u32*  comp     = (u32*)w;   w += (size_t)4 * NN * sizeof(u32);      // 0.8 MB
  u32*  hookTo   = (u32*)w;   w += (size_t)4 * NN * sizeof(u32);      // 0.8 MB
  u32*  msfCnt   = (u32*)w;   w += 4 * sizeof(u32);
  u32*  done     = (u32*)w;   w += 4 * sizeof(u32);
  u32*  changed  = (u32*)w;   w += 4 * sizeof(u32);
  u32*  maxv     = (u32*)w;   w += 4 * sizeof(u32);

  const size_t need = (size_t)(w - (char*)d_ws);
  if (ws_size < need) return;

  const int nodeBlocks = (NN + 255) / 256;
  const int edgeBlocks = (NE + 255) / 256;

  setup_kernel<<<dim3(SEGN / 256, 4), dim3(256), 0, stream>>>(
      msf, comp, minOut, hookTo, msfCnt, done, changed, maxv);
  mlp_kernel<<<dim3((NN + 63) / 64), dim3(256), 0, stream>>>(X, W1, b1, W2, b2, filt);
  maxv_kernel<<<dim3(nodeBlocks, 1), dim3(256), 0, stream>>>(filt, maxv);
  nodeprep_kernel<<<dim3(SEGN / 256, 4), dim3(256), 0, stream>>>(filt, nodekeys);

  // node sort (4 segments of SEGN): rank space
  bitonic_lds_full<<<dim3(SEGN / 4096, 4), dim3(256), 0, stream>>>(nodekeys, SEGN);
  for (int k = 8192; k <= SEGN; k <<= 1) {
    for (int j = k >> 1; j >= 4096; j >>= 1)
      bitonic_global<<<dim3(SEGN / 256, 4), dim3(256), 0, stream>>>(nodekeys, SEGN, k, j);
    bitonic_lds_tail<<<dim3(SEGN / 4096, 4), dim3(256), 0, stream>>>(nodekeys, SEGN, k);
  }

  rank_kernel<<<dim3(SEGN / 256, 4), dim3(256), 0, stream>>>(nodekeys, rankOf, nodeOf);
  init_kernel<<<dim3(nodeBlocks, 4), dim3(256), 0, stream>>>(filt, maxv, out);
  prep_kernel<<<dim3(edgeBlocks, 1), dim3(256), 0, stream>>>(EI, filt, rankOf, erank, ekeys);

  // Boruvka MSF (parallel); done-flag turns converged rounds into no-ops
  for (int r = 0; r < BOR_ROUNDS; r++) {
    bor_edges<<<dim3(edgeBlocks, 4), dim3(256), 0, stream>>>(ekeys, erank, comp, minOut, done);
    bor_choose<<<dim3(nodeBlocks, 4), dim3(256), 0, stream>>>(erank, comp, minOut, hookTo,
                                                              msf, msfCnt, done, changed);
    bor_apply<<<dim3(nodeBlocks, 4), dim3(256), 0, stream>>>(comp, hookTo, done, changed);
    bor_jump<<<dim3(nodeBlocks, 4), dim3(256), 0, stream>>>(comp, minOut, done);
  }

  // sort MSF keys (4 segments of SEGN; ~0ull padding sorts to the end)
  bitonic_lds_full<<<dim3(SEGN / 4096, 4), dim3(256), 0, stream>>>(msf, SEGN);
  for (int k = 8192; k <= SEGN; k <<= 1) {
    for (int j = k >> 1; j >= 4096; j >>= 1)
      bitonic_global<<<dim3(SEGN / 256, 4), dim3(256), 0, stream>>>(msf, SEGN, k, j);
    bitonic_lds_tail<<<dim3(SEGN / 4096, 4), dim3(256), 0, stream>>>(msf, SEGN, k);
  }

  uf_kernel<<<dim3(4), dim3(64), 0, stream>>>(msf, msfCnt, erank, nodeOf, out);
}

// Round 6
// 11296.925 us; speedup vs baseline: 8.4268x; 1.2265x over previous
//
#include <hip/hip_runtime.h>
#include <stdint.h>

#define NN 50000
#define NE 200000
#define NFEAT 512
#define NHID 256
#define SEGN 65536   /* 2^16 >= NN: node-key sort + MSF-key sort segment */
#define BOR_ROUNDS 16 /* components at least halve per round: 2^16 > 50000 */

typedef unsigned long long u64;
typedef unsigned int u32;
typedef unsigned short u16;
typedef unsigned char u8;

// order-preserving float -> u32 (strictly monotone), exact round-trip
__device__ __forceinline__ u32 encf(float x) {
  u32 u = __float_as_uint(x);
  return (u & 0x80000000u) ? ~u : (u | 0x80000000u);
}
__device__ __forceinline__ float decf(u32 y) {
  u32 u = (y & 0x80000000u) ? (y ^ 0x80000000u) : ~y;
  return __uint_as_float(u);
}

#define SWZ(c) ((c) ^ ((((c) >> 5) & 7) << 2))

// ---------------- filt = relu(X@W1 + b1) @ W2 + b2  -> (NN x 4) f32 ----------------
__global__ __launch_bounds__(256) void mlp_kernel(
    const float* __restrict__ X, const float* __restrict__ W1,
    const float* __restrict__ b1, const float* __restrict__ W2,
    const float* __restrict__ b2, float* __restrict__ filt)
{
  __shared__ float As[64][33];
  __shared__ float Ws[32][256];
  __shared__ float W2s[256][4];

  const int tid = threadIdx.x;
  const int row0 = blockIdx.x * 64;
  const int tr = tid >> 4, tc = tid & 15;

  for (int i = tid; i < NHID * 4; i += 256) W2s[i >> 2][i & 3] = W2[i];

  float4 acc[4][4];
  #pragma unroll
  for (int i = 0; i < 4; i++)
    #pragma unroll
    for (int q = 0; q < 4; q++) acc[i][q] = make_float4(0.f, 0.f, 0.f, 0.f);

  for (int k0 = 0; k0 < NFEAT; k0 += 32) {
    __syncthreads();
    {
      const int r = tid >> 3, c4 = (tid & 7) << 2;
      #pragma unroll
      for (int rr = 0; rr < 2; rr++) {
        const int row = r + rr * 32;
        const int grow = row0 + row;
        float4 v = make_float4(0.f, 0.f, 0.f, 0.f);
        if (grow < NN) v = *(const float4*)&X[(size_t)grow * NFEAT + k0 + c4];
        As[row][c4 + 0] = v.x; As[row][c4 + 1] = v.y;
        As[row][c4 + 2] = v.z; As[row][c4 + 3] = v.w;
      }
      const int wr = tid >> 6, wc4 = (tid & 63) << 2;
      const int pc = SWZ(wc4);
      #pragma unroll
      for (int rr = 0; rr < 8; rr++) {
        const int rowk = wr + rr * 4;
        float4 v = *(const float4*)&W1[(size_t)(k0 + rowk) * NHID + wc4];
        *(float4*)&Ws[rowk][pc] = v;
      }
    }
    __syncthreads();
    #pragma unroll 8
    for (int kk = 0; kk < 32; kk++) {
      const float a0 = As[tr * 4 + 0][kk], a1 = As[tr * 4 + 1][kk],
                  a2 = As[tr * 4 + 2][kk], a3 = As[tr * 4 + 3][kk];
      #pragma unroll
      for (int q = 0; q < 4; q++) {
        const int col = tc * 16 + q * 4;
        const float4 wv = *(const float4*)&Ws[kk][SWZ(col)];
        acc[0][q].x += a0 * wv.x; acc[0][q].y += a0 * wv.y;
        acc[0][q].z += a0 * wv.z; acc[0][q].w += a0 * wv.w;
        acc[1][q].x += a1 * wv.x; acc[1][q].y += a1 * wv.y;
        acc[1][q].z += a1 * wv.z; acc[1][q].w += a1 * wv.w;
        acc[2][q].x += a2 * wv.x; acc[2][q].y += a2 * wv.y;
        acc[2][q].z += a2 * wv.z; acc[2][q].w += a2 * wv.w;
        acc[3][q].x += a3 * wv.x; acc[3][q].y += a3 * wv.y;
        acc[3][q].w += a3 * wv.w; acc[3][q].z += a3 * wv.z;
      }
    }
  }

  float p[4][4];
  #pragma unroll
  for (int i = 0; i < 4; i++)
    #pragma unroll
    for (int f = 0; f < 4; f++) p[i][f] = 0.f;

  #pragma unroll
  for (int q = 0; q < 4; q++) {
    const int colb = tc * 16 + q * 4;
    float bb[4];
    #pragma unroll
    for (int j = 0; j < 4; j++) bb[j] = b1[colb + j];
    #pragma unroll
    for (int i = 0; i < 4; i++) {
      float h[4] = {acc[i][q].x + bb[0], acc[i][q].y + bb[1],
                    acc[i][q].z + bb[2], acc[i][q].w + bb[3]};
      #pragma unroll
      for (int j = 0; j < 4; j++) {
        const float hh = fmaxf(h[j], 0.f);
        #pragma unroll
        for (int f = 0; f < 4; f++) p[i][f] += hh * W2s[colb + j][f];
      }
    }
  }

  #pragma unroll
  for (int m = 1; m < 16; m <<= 1)
    #pragma unroll
    for (int i = 0; i < 4; i++)
      #pragma unroll
      for (int f = 0; f < 4; f++)
        p[i][f] += __shfl_xor(p[i][f], m, 64);

  if (tc == 0) {
    const float c0 = b2[0], c1 = b2[1], c2 = b2[2], c3 = b2[3];
    #pragma unroll
    for (int i = 0; i < 4; i++) {
      const int row = row0 + tr * 4 + i;
      if (row < NN) {
        float4 o = make_float4(p[i][0] + c0, p[i][1] + c1, p[i][2] + c2, p[i][3] + c3);
        *(float4*)&filt[(size_t)row * 4] = o;
      }
    }
  }
}

// ---------------- setup: msf padding, Boruvka state, dead flags, counters ----------------
__global__ __launch_bounds__(256) void setup_kernel(
    u64* __restrict__ msf, u32* __restrict__ comp, u64* __restrict__ minOut,
    u32* __restrict__ hookTo, u8* __restrict__ dead, u32* __restrict__ msfCnt,
    u32* __restrict__ done, u32* __restrict__ changed, u32* __restrict__ maxv)
{
  const int j = blockIdx.x * 256 + threadIdx.x;
  const int f = blockIdx.y;
  msf[(size_t)f * SEGN + j] = ~0ull;
  if (j < NN) {
    comp[(size_t)f * NN + j] = (u32)j;
    minOut[(size_t)f * NN + j] = ~0ull;
    hookTo[(size_t)f * NN + j] = (u32)j;
  }
  for (int e = j; e < NE; e += SEGN) dead[(size_t)f * NE + e] = 0;
  if (j == 0) {
    msfCnt[f] = 0u; done[f] = 0u; changed[f] = 0u;
    if (f == 0) { maxv[0] = 0u; maxv[1] = 0u; maxv[2] = 0u; maxv[3] = 0u; }
  }
}

__global__ __launch_bounds__(256) void maxv_kernel(const float* __restrict__ filt,
                                                   u32* __restrict__ maxv)
{
  __shared__ u32 lm[4];
  if (threadIdx.x < 4) lm[threadIdx.x] = 0u;
  __syncthreads();
  const int n = blockIdx.x * 256 + threadIdx.x;
  if (n < NN) {
    const float4 v = *(const float4*)&filt[(size_t)n * 4];
    atomicMax(&lm[0], encf(v.x));
    atomicMax(&lm[1], encf(v.y));
    atomicMax(&lm[2], encf(v.z));
    atomicMax(&lm[3], encf(v.w));
  }
  __syncthreads();
  if (threadIdx.x < 4) atomicMax(&maxv[threadIdx.x], lm[threadIdx.x]);
}

// ---------------- node sort keys: (enc(v), node), padded ----------------
__global__ __launch_bounds__(256) void nodeprep_kernel(const float* __restrict__ filt,
                                                       u64* __restrict__ nodekeys)
{
  const int n = blockIdx.x * 256 + threadIdx.x;
  const int f = blockIdx.y;
  if (n < NN) {
    const float v = filt[(size_t)n * 4 + f];
    nodekeys[(size_t)f * SEGN + n] = ((u64)encf(v) << 32) | (u32)n;
  } else if (n < SEGN) {
    nodekeys[(size_t)f * SEGN + n] = ~0ull;
  }
}

// ---------------- rank scatter ----------------
__global__ __launch_bounds__(256) void rank_kernel(const u64* __restrict__ nodekeys,
                                                   u32* __restrict__ rankOf,
                                                   u32* __restrict__ nodeOf)
{
  const int j = blockIdx.x * 256 + threadIdx.x;
  const int f = blockIdx.y;
  if (j < NN) {
    const u64 kk = nodekeys[(size_t)f * SEGN + j];
    const u32 node = (u32)(kk & 0xffffffffu);
    rankOf[(size_t)f * NN + node] = (u32)j;
    nodeOf[(size_t)f * SEGN + j] = node;
  }
}

// ---------------- births + essential deaths ----------------
__global__ __launch_bounds__(256) void init_kernel(
    const float* __restrict__ filt, const u32* __restrict__ maxv,
    float* __restrict__ out)
{
  const int n = blockIdx.x * 256 + threadIdx.x;
  const int f = blockIdx.y;
  if (n < NN) {
    const size_t idx = (size_t)f * NN + n;
    out[idx * 2 + 0] = filt[(size_t)n * 4 + f];
    out[idx * 2 + 1] = decf(maxv[f]);
  }
}

// ---------------- per-edge keys + rank-space endpoints ----------------
__global__ __launch_bounds__(256) void prep_kernel(
    const int* __restrict__ ei, const float* __restrict__ filt,
    const u32* __restrict__ rankOf,
    u32* __restrict__ erank, u64* __restrict__ ekeys)
{
  const int e = blockIdx.x * 256 + threadIdx.x;
  if (e >= NE) return;
  const int s = ei[e];
  const int d = ei[NE + e];
  const float4 vs = *(const float4*)&filt[(size_t)s * 4];
  const float4 vd = *(const float4*)&filt[(size_t)d * 4];
  ekeys[0 * (size_t)NE + e] = ((u64)encf(fmaxf(vs.x, vd.x)) << 32) | (u32)e;
  ekeys[1 * (size_t)NE + e] = ((u64)encf(fmaxf(vs.y, vd.y)) << 32) | (u32)e;
  ekeys[2 * (size_t)NE + e] = ((u64)encf(fmaxf(vs.z, vd.z)) << 32) | (u32)e;
  ekeys[3 * (size_t)NE + e] = ((u64)encf(fmaxf(vs.w, vd.w)) << 32) | (u32)e;
  #pragma unroll
  for (int f = 0; f < 4; f++) {
    const u32 ru = rankOf[(size_t)f * NN + s];
    const u32 rt = rankOf[(size_t)f * NN + d];
    erank[(size_t)f * NE + e] = (ru << 16) | rt;
  }
}

// ---------------- Boruvka round: per-edge min-outgoing-key selection ----------------
__global__ __launch_bounds__(256) void bor_edges(
    const u64* __restrict__ ekeys, const u32* __restrict__ erank,
    const u32* __restrict__ comp, u64* __restrict__ minOut,
    u8* __restrict__ dead, const u32* __restrict__ done)
{
  const int f = blockIdx.y;
  if (done[f]) return;
  const int e = blockIdx.x * 256 + threadIdx.x;
  if (e >= NE) return;
  if (dead[(size_t)f * NE + e]) return;    // settled internal edge: skip all gathers
  const u32 pr = erank[(size_t)f * NE + e];
  const u32* cf = comp + (size_t)f * NN;
  u32 a = cf[pr >> 16]; a = cf[a];
  u32 b = cf[pr & 0xffffu]; b = cf[b];
  if (a == b) { dead[(size_t)f * NE + e] = 1; return; }  // connectivity is monotone
  const u64 k = ekeys[(size_t)f * NE + e];
  atomicMin(&minOut[(size_t)f * NN + a], k);
  atomicMin(&minOut[(size_t)f * NN + b], k);
}

// ---------------- Boruvka round: choose hooks + record MSF edges ----------------
__global__ __launch_bounds__(256) void bor_choose(
    const u32* __restrict__ erank, const u32* __restrict__ comp,
    const u64* __restrict__ minOut, u32* __restrict__ hookTo,
    u64* __restrict__ msf, u32* __restrict__ msfCnt,
    const u32* __restrict__ done, u32* __restrict__ changed)
{
  const int f = blockIdx.y;
  if (done[f]) return;
  const int r = blockIdx.x * 256 + threadIdx.x;
  if (r >= NN) return;
  const u32* cf = comp + (size_t)f * NN;
  if (cf[r] != (u32)r) return;                       // roots only
  const u64 k = minOut[(size_t)f * NN + r];
  if (k == ~0ull) return;                            // isolated component
  const u32 e = (u32)(k & 0xffffffffu);
  const u32 pr = erank[(size_t)f * NE + e];
  u32 a = cf[pr >> 16]; a = cf[a];
  u32 b = cf[pr & 0xffffu]; b = cf[b];
  const u32 other = (a == (u32)r) ? b : a;
  // mutual-min pair: only the larger id hooks (records once); chains otherwise
  // strictly decrease in key along hooks -> acyclic
  if (minOut[(size_t)f * NN + other] == k && other > (u32)r) return;
  hookTo[(size_t)f * NN + r] = other;
  changed[f] = 1u;
  const u32 slot = atomicAdd(&msfCnt[f], 1u);
  msf[(size_t)f * SEGN + slot] = k;
}

// ---------------- Boruvka round: apply hooks (clean snapshot) + done flag ----------------
__global__ __launch_bounds__(256) void bor_apply(
    u32* __restrict__ comp, u32* __restrict__ hookTo,
    u32* __restrict__ done, u32* __restrict__ changed)
{
  const int f = blockIdx.y;
  if (done[f]) return;
  const int r = blockIdx.x * 256 + threadIdx.x;
  if (r >= NN) return;
  const u32 h = hookTo[(size_t)f * NN + r];
  if (h != (u32)r) {
    comp[(size_t)f * NN + r] = h;
    hookTo[(size_t)f * NN + r] = (u32)r;
  }
  if (r == 0) { if (changed[f] == 0u) done[f] = 1u; changed[f] = 0u; }
}

// ---------------- Boruvka round: pointer-jump full compression + minOut reset ----
__global__ __launch_bounds__(256) void bor_jump(
    u32* __restrict__ comp, u64* __restrict__ minOut, const u32* __restrict__ done)
{
  const int f = blockIdx.y;
  if (done[f]) return;
  const int x = blockIdx.x * 256 + threadIdx.x;
  if (x >= NN) return;
  u32* cf = comp + (size_t)f * NN;
  u32 p = cf[x];
  u32 g = cf[p];
  while (p != g) { p = g; g = cf[p]; }   // concurrent writes only shortcut
  cf[x] = p;
  minOut[(size_t)f * NN + x] = ~0ull;
}

// ---------------- bitonic: fused LDS phases k=2..4096 ----------------
__global__ __launch_bounds__(256) void bitonic_lds_full(u64* __restrict__ keys, int seglen)
{
  __shared__ u64 sh[4096];
  u64* a = keys + (size_t)blockIdx.y * seglen + (size_t)blockIdx.x * 4096;
  const int gbase = blockIdx.x * 4096;
  for (int i = threadIdx.x; i < 4096; i += 256) sh[i] = a[i];
  __syncthreads();
  for (int k = 2; k <= 4096; k <<= 1) {
    for (int j = k >> 1; j >= 1; j >>= 1) {
      for (int p = threadIdx.x; p < 2048; p += 256) {
        const int i = ((p & ~(j - 1)) << 1) | (p & (j - 1));
        const int ixj = i + j;
        const bool up = (((gbase + i) & k) == 0);
        const u64 x = sh[i], y = sh[ixj];
        if ((x > y) == up) { sh[i] = y; sh[ixj] = x; }
      }
      __syncthreads();
    }
  }
  for (int i = threadIdx.x; i < 4096; i += 256) a[i] = sh[i];
}

// ---------------- bitonic: fused LDS tail (fixed k, j=2048..1) ----------------
__global__ __launch_bounds__(256) void bitonic_lds_tail(u64* __restrict__ keys, int seglen, int k)
{
  __shared__ u64 sh[4096];
  u64* a = keys + (size_t)blockIdx.y * seglen + (size_t)blockIdx.x * 4096;
  const int gbase = blockIdx.x * 4096;
  for (int i = threadIdx.x; i < 4096; i += 256) sh[i] = a[i];
  __syncthreads();
  for (int j = 2048; j >= 1; j >>= 1) {
    for (int p = threadIdx.x; p < 2048; p += 256) {
      const int i = ((p & ~(j - 1)) << 1) | (p & (j - 1));
      const int ixj = i + j;
      const bool up = (((gbase + i) & k) == 0);
      const u64 x = sh[i], y = sh[ixj];
      if ((x > y) == up) { sh[i] = y; sh[ixj] = x; }
    }
    __syncthreads();
  }
  for (int i = threadIdx.x; i < 4096; i += 256) a[i] = sh[i];
}

// ---------------- bitonic: one global pass (j >= 4096) ----------------
__global__ __launch_bounds__(256) void bitonic_global(u64* __restrict__ keys, int seglen,
                                                      int k, int j)
{
  const int i = blockIdx.x * 256 + threadIdx.x;
  u64* a = keys + (size_t)blockIdx.y * seglen;
  const int ixj = i ^ j;
  if (ixj > i) {
    const u64 x = a[i], y = a[ixj];
    const bool up = ((i & k) == 0);
    if ((x > y) == up) { a[i] = y; a[ixj] = x; }
  }
}

// ---------------- rank-space Kruskal over sorted MSF edges only ----------------
__global__ __launch_bounds__(64) void uf_kernel(
    const u64* __restrict__ msf, const u32* __restrict__ msfCnt,
    const u32* __restrict__ erank, const u32* __restrict__ nodeOf,
    float* __restrict__ out)
{
  __shared__ u16 par[NN];   // 100 KB LDS: ranks < 50000 < 65536
  const int f = blockIdx.x;
  const int lane = threadIdx.x;
  const u32* ndOf = nodeOf + (size_t)f * SEGN;
  const u64* ks = msf + (size_t)f * SEGN;
  const u32* er = erank + (size_t)f * NE;
  float* outf = out + (size_t)f * NN * 2;
  const int cnt = (int)msfCnt[f];    // <= NN-1

  u32* par32 = (u32*)par;
  for (int j = lane; j < NN / 2; j += 64)
    par32[j] = ((u32)(2 * j + 1) << 16) | (u32)(2 * j);
  __syncthreads();

  u64 key = ~0ull; u32 pr = 0u;
  if (cnt > 0) {
    key = ks[lane];
    const u32 e0 = (u32)(key & 0xffffffffu);
    pr = (e0 < (u32)NE) ? er[e0] : 0u;
  }

  for (int base = 0; base < cnt; base += 64) {
    // prefetch next batch's keys early (overlaps finds)
    u64 nkey = ~0ull;
    if (base + 64 < cnt) nkey = ks[base + 64 + lane];

    const bool live = (base + lane < cnt);
    int u = 0, t = 0;
    if (live) { u = (int)(pr >> 16); t = (int)(pr & 0xffffu); }

    // dual interleaved path-halving find in LDS (snapshot before batch merges)
    int ru = u, rt = t;
    u32 pu = par[ru], pt = par[rt];
    while (pu != (u32)ru || pt != (u32)rt) {
      const u32 gu = par[pu];
      const u32 gt = par[pt];
      if (pu != (u32)ru) { par[ru] = (u16)gu; ru = (int)gu; }
      if (pt != (u32)rt) { par[rt] = (u16)gt; rt = (int)gt; }
      pu = par[ru]; pt = par[rt];
    }

    // prefetch next batch's endpoint ranks (overlaps merge loop)
    u32 npr = 0u;
    if (base + 64 < cnt) {
      const u32 ne = (u32)(nkey & 0xffffffffu);
      if (ne < (u32)NE) npr = er[ne];
    }

    // in-order merge resolution: registers + shuffles ONLY (no memory waits on
    // the serial chain; death writes deferred to the parallel epilogue below)
    u64 cand = __ballot(live && (ru != rt));
    int mu = ru, mt = rt;
    int myLose = -1;
    while (cand) {
      const int l = __ffsll((long long)cand) - 1;
      cand &= (cand - 1);
      const int a = __shfl(mu, l);
      const int b = __shfl(mt, l);
      if (a != b) {
        const int win = (a < b) ? a : b;
        const int lose = (a < b) ? b : a;
        if (lane == l) {
          par[lose] = (u16)win;          // root merge (LDS, no wait needed yet)
          myLose = lose;
        }
        mu = (mu == lose) ? win : mu;
        mt = (mt == lose) ? win : mt;
      }
    }

    // parallel epilogue: one gather + one store per merging lane, one vmcnt
    // stall per batch instead of per merge (each rank loses exactly once ->
    // unique writer per output slot)
    if (myLose >= 0) {
      const u32 node = ndOf[myLose];
      outf[(size_t)node * 2 + 1] = decf((u32)(key >> 32));
    }

    // commit this batch's LDS writes before next batch's reads
    asm volatile("s_waitcnt lgkmcnt(0)" ::: "memory");
    __builtin_amdgcn_sched_barrier(0);
    key = nkey; pr = npr;
  }
}

extern "C" void kernel_launch(void* const* d_in, const int* in_sizes, int n_in,
                              void* d_out, int out_size, void* d_ws, size_t ws_size,
                              hipStream_t stream)
{
  const float* X  = (const float*)d_in[0];
  const float* W1 = (const float*)d_in[1];
  const float* b1 = (const float*)d_in[2];
  const float* W2 = (const float*)d_in[3];
  const float* b2 = (const float*)d_in[4];
  const int*   EI = (const int*)d_in[5];   // int32 per harness contract
  float* out = (float*)d_out;

  char* w = (char*)d_ws;
  u64*  ekeys    = (u64*)w;   w += (size_t)4 * NE * sizeof(u64);      // 6.4 MB
  u64*  nodekeys = (u64*)w;   w += (size_t)4 * SEGN * sizeof(u64);    // 2 MB
  u64*  minOut   = (u64*)w;   w += (size_t)4 * NN * sizeof(u64);      // 1.6 MB
  u64*  msf      = (u64*)w;   w += (size_t)4 * SEGN * sizeof(u64);    // 2 MB
  float* filt    = (float*)w; w += (size_t)NN * 4 * sizeof(float);    // 0.8 MB
  u32*  rankOf   = (u32*)w;   w += (size_t)4 * NN * sizeof(u32);      // 0.8 MB
  u32*  nodeOf   = (u32*)w;   w += (size_t)4 * SEGN * sizeof(u32);    // 1 MB
  u32*  erank    = (u32*)w;   w += (size_t)4 * NE * sizeof(u32);      // 3.2 MB
  u32*  comp     = (u32*)w;   w += (size_t)4 * NN * sizeof(u32);      // 0.8 MB
  u32*  hookTo   = (u32*)w;   w += (size_t)4 * NN * sizeof(u32);      // 0.8 MB
  u8*   dead     = (u8*)w;    w += (size_t)4 * NE * sizeof(u8);       // 0.8 MB
  u32*  msfCnt   = (u32*)w;   w += 4 * sizeof(u32);
  u32*  done     = (u32*)w;   w += 4 * sizeof(u32);
  u32*  changed  = (u32*)w;   w += 4 * sizeof(u32);
  u32*  maxv     = (u32*)w;   w += 4 * sizeof(u32);

  const size_t need = (size_t)(w - (char*)d_ws);
  if (ws_size < need) return;

  const int nodeBlocks = (NN + 255) / 256;
  const int edgeBlocks = (NE + 255) / 256;

  setup_kernel<<<dim3(SEGN / 256, 4), dim3(256), 0, stream>>>(
      msf, comp, minOut, hookTo, dead, msfCnt, done, changed, maxv);
  mlp_kernel<<<dim3((NN + 63) / 64), dim3(256), 0, stream>>>(X, W1, b1, W2, b2, filt);
  maxv_kernel<<<dim3(nodeBlocks, 1), dim3(256), 0, stream>>>(filt, maxv);
  nodeprep_kernel<<<dim3(SEGN / 256, 4), dim3(256), 0, stream>>>(filt, nodekeys);

  // node sort (4 segments of SEGN): rank space
  bitonic_lds_full<<<dim3(SEGN / 4096, 4), dim3(256), 0, stream>>>(nodekeys, SEGN);
  for (int k = 8192; k <= SEGN; k <<= 1) {
    for (int j = k >> 1; j >= 4096; j >>= 1)
      bitonic_global<<<dim3(SEGN / 256, 4), dim3(256), 0, stream>>>(nodekeys, SEGN, k, j);
    bitonic_lds_tail<<<dim3(SEGN / 4096, 4), dim3(256), 0, stream>>>(nodekeys, SEGN, k);
  }

  rank_kernel<<<dim3(SEGN / 256, 4), dim3(256), 0, stream>>>(nodekeys, rankOf, nodeOf);
  init_kernel<<<dim3(nodeBlocks, 4), dim3(256), 0, stream>>>(filt, maxv, out);
  prep_kernel<<<dim3(edgeBlocks, 1), dim3(256), 0, stream>>>(EI, filt, rankOf, erank, ekeys);

  // Boruvka MSF (parallel); done-flag turns converged rounds into no-ops
  for (int r = 0; r < BOR_ROUNDS; r++) {
    bor_edges<<<dim3(edgeBlocks, 4), dim3(256), 0, stream>>>(ekeys, erank, comp, minOut,
                                                             dead, done);
    bor_choose<<<dim3(nodeBlocks, 4), dim3(256), 0, stream>>>(erank, comp, minOut, hookTo,
                                                              msf, msfCnt, done, changed);
    bor_apply<<<dim3(nodeBlocks, 4), dim3(256), 0, stream>>>(comp, hookTo, done, changed);
    bor_jump<<<dim3(nodeBlocks, 4), dim3(256), 0, stream>>>(comp, minOut, done);
  }

  // sort MSF keys (4 segments of SEGN; ~0ull padding sorts to the end)
  bitonic_lds_full<<<dim3(SEGN / 4096, 4), dim3(256), 0, stream>>>(msf, SEGN);
  for (int k = 8192; k <= SEGN; k <<= 1) {
    for (int j = k >> 1; j >= 4096; j >>= 1)
      bitonic_global<<<dim3(SEGN / 256, 4), dim3(256), 0, stream>>>(msf, SEGN, k, j);
    bitonic_lds_tail<<<dim3(SEGN / 4096, 4), dim3(256), 0, stream>>>(msf, SEGN, k);
  }

  uf_kernel<<<dim3(4), dim3(64), 0, stream>>>(msf, msfCnt, erank, nodeOf, out);
}

// Round 7
// 5152.572 us; speedup vs baseline: 18.4755x; 2.1925x over previous
//
#include <hip/hip_runtime.h>
#include <stdint.h>

#define NN 50000
#define NE 200000
#define NFEAT 512
#define NHID 256
#define SEGN 65536    /* 2^16 >= NN: node-key sort + MSF-key sort segment */
#define BOR_ROUNDS 16 /* components at least halve per round: 2^16 > 50000 */
#define NPART 8       /* partitions of the sorted-MSF Kruskal scan */
#define CCMAXR 32     /* max hook+jump rounds per prefix-CC stage */

typedef unsigned long long u64;
typedef unsigned int u32;
typedef unsigned short u16;
typedef unsigned char u8;

// order-preserving float -> u32 (strictly monotone), exact round-trip
__device__ __forceinline__ u32 encf(float x) {
  u32 u = __float_as_uint(x);
  return (u & 0x80000000u) ? ~u : (u | 0x80000000u);
}
__device__ __forceinline__ float decf(u32 y) {
  u32 u = (y & 0x80000000u) ? (y ^ 0x80000000u) : ~y;
  return __uint_as_float(u);
}

#define SWZ(c) ((c) ^ ((((c) >> 5) & 7) << 2))

// ---------------- filt = relu(X@W1 + b1) @ W2 + b2  -> (NN x 4) f32 ----------------
__global__ __launch_bounds__(256) void mlp_kernel(
    const float* __restrict__ X, const float* __restrict__ W1,
    const float* __restrict__ b1, const float* __restrict__ W2,
    const float* __restrict__ b2, float* __restrict__ filt)
{
  __shared__ float As[64][33];
  __shared__ float Ws[32][256];
  __shared__ float W2s[256][4];

  const int tid = threadIdx.x;
  const int row0 = blockIdx.x * 64;
  const int tr = tid >> 4, tc = tid & 15;

  for (int i = tid; i < NHID * 4; i += 256) W2s[i >> 2][i & 3] = W2[i];

  float4 acc[4][4];
  #pragma unroll
  for (int i = 0; i < 4; i++)
    #pragma unroll
    for (int q = 0; q < 4; q++) acc[i][q] = make_float4(0.f, 0.f, 0.f, 0.f);

  for (int k0 = 0; k0 < NFEAT; k0 += 32) {
    __syncthreads();
    {
      const int r = tid >> 3, c4 = (tid & 7) << 2;
      #pragma unroll
      for (int rr = 0; rr < 2; rr++) {
        const int row = r + rr * 32;
        const int grow = row0 + row;
        float4 v = make_float4(0.f, 0.f, 0.f, 0.f);
        if (grow < NN) v = *(const float4*)&X[(size_t)grow * NFEAT + k0 + c4];
        As[row][c4 + 0] = v.x; As[row][c4 + 1] = v.y;
        As[row][c4 + 2] = v.z; As[row][c4 + 3] = v.w;
      }
      const int wr = tid >> 6, wc4 = (tid & 63) << 2;
      const int pc = SWZ(wc4);
      #pragma unroll
      for (int rr = 0; rr < 8; rr++) {
        const int rowk = wr + rr * 4;
        float4 v = *(const float4*)&W1[(size_t)(k0 + rowk) * NHID + wc4];
        *(float4*)&Ws[rowk][pc] = v;
      }
    }
    __syncthreads();
    #pragma unroll 8
    for (int kk = 0; kk < 32; kk++) {
      const float a0 = As[tr * 4 + 0][kk], a1 = As[tr * 4 + 1][kk],
                  a2 = As[tr * 4 + 2][kk], a3 = As[tr * 4 + 3][kk];
      #pragma unroll
      for (int q = 0; q < 4; q++) {
        const int col = tc * 16 + q * 4;
        const float4 wv = *(const float4*)&Ws[kk][SWZ(col)];
        acc[0][q].x += a0 * wv.x; acc[0][q].y += a0 * wv.y;
        acc[0][q].z += a0 * wv.z; acc[0][q].w += a0 * wv.w;
        acc[1][q].x += a1 * wv.x; acc[1][q].y += a1 * wv.y;
        acc[1][q].z += a1 * wv.z; acc[1][q].w += a1 * wv.w;
        acc[2][q].x += a2 * wv.x; acc[2][q].y += a2 * wv.y;
        acc[2][q].z += a2 * wv.z; acc[2][q].w += a2 * wv.w;
        acc[3][q].x += a3 * wv.x; acc[3][q].y += a3 * wv.y;
        acc[3][q].w += a3 * wv.w; acc[3][q].z += a3 * wv.z;
      }
    }
  }

  float p[4][4];
  #pragma unroll
  for (int i = 0; i < 4; i++)
    #pragma unroll
    for (int f = 0; f < 4; f++) p[i][f] = 0.f;

  #pragma unroll
  for (int q = 0; q < 4; q++) {
    const int colb = tc * 16 + q * 4;
    float bb[4];
    #pragma unroll
    for (int j = 0; j < 4; j++) bb[j] = b1[colb + j];
    #pragma unroll
    for (int i = 0; i < 4; i++) {
      float h[4] = {acc[i][q].x + bb[0], acc[i][q].y + bb[1],
                    acc[i][q].z + bb[2], acc[i][q].w + bb[3]};
      #pragma unroll
      for (int j = 0; j < 4; j++) {
        const float hh = fmaxf(h[j], 0.f);
        #pragma unroll
        for (int f = 0; f < 4; f++) p[i][f] += hh * W2s[colb + j][f];
      }
    }
  }

  #pragma unroll
  for (int m = 1; m < 16; m <<= 1)
    #pragma unroll
    for (int i = 0; i < 4; i++)
      #pragma unroll
      for (int f = 0; f < 4; f++)
        p[i][f] += __shfl_xor(p[i][f], m, 64);

  if (tc == 0) {
    const float c0 = b2[0], c1 = b2[1], c2 = b2[2], c3 = b2[3];
    #pragma unroll
    for (int i = 0; i < 4; i++) {
      const int row = row0 + tr * 4 + i;
      if (row < NN) {
        float4 o = make_float4(p[i][0] + c0, p[i][1] + c1, p[i][2] + c2, p[i][3] + c3);
        *(float4*)&filt[(size_t)row * 4] = o;
      }
    }
  }
}

// ---------------- setup: msf padding, Boruvka state, dead flags, counters ----------------
__global__ __launch_bounds__(256) void setup_kernel(
    u64* __restrict__ msf, u32* __restrict__ comp, u64* __restrict__ minOut,
    u32* __restrict__ hookTo, u8* __restrict__ dead, u32* __restrict__ msfCnt,
    u32* __restrict__ done, u32* __restrict__ changed, u32* __restrict__ maxv)
{
  const int j = blockIdx.x * 256 + threadIdx.x;
  const int f = blockIdx.y;
  msf[(size_t)f * SEGN + j] = ~0ull;
  if (j < NN) {
    comp[(size_t)f * NN + j] = (u32)j;
    minOut[(size_t)f * NN + j] = ~0ull;
    hookTo[(size_t)f * NN + j] = (u32)j;
  }
  for (int e = j; e < NE; e += SEGN) dead[(size_t)f * NE + e] = 0;
  if (j == 0) {
    msfCnt[f] = 0u; done[f] = 0u; changed[f] = 0u;
    if (f == 0) { maxv[0] = 0u; maxv[1] = 0u; maxv[2] = 0u; maxv[3] = 0u; }
  }
}

__global__ __launch_bounds__(256) void maxv_kernel(const float* __restrict__ filt,
                                                   u32* __restrict__ maxv)
{
  __shared__ u32 lm[4];
  if (threadIdx.x < 4) lm[threadIdx.x] = 0u;
  __syncthreads();
  const int n = blockIdx.x * 256 + threadIdx.x;
  if (n < NN) {
    const float4 v = *(const float4*)&filt[(size_t)n * 4];
    atomicMax(&lm[0], encf(v.x));
    atomicMax(&lm[1], encf(v.y));
    atomicMax(&lm[2], encf(v.z));
    atomicMax(&lm[3], encf(v.w));
  }
  __syncthreads();
  if (threadIdx.x < 4) atomicMax(&maxv[threadIdx.x], lm[threadIdx.x]);
}

// ---------------- node sort keys: (enc(v), node), padded ----------------
__global__ __launch_bounds__(256) void nodeprep_kernel(const float* __restrict__ filt,
                                                       u64* __restrict__ nodekeys)
{
  const int n = blockIdx.x * 256 + threadIdx.x;
  const int f = blockIdx.y;
  if (n < NN) {
    const float v = filt[(size_t)n * 4 + f];
    nodekeys[(size_t)f * SEGN + n] = ((u64)encf(v) << 32) | (u32)n;
  } else if (n < SEGN) {
    nodekeys[(size_t)f * SEGN + n] = ~0ull;
  }
}

// ---------------- rank scatter ----------------
__global__ __launch_bounds__(256) void rank_kernel(const u64* __restrict__ nodekeys,
                                                   u32* __restrict__ rankOf,
                                                   u32* __restrict__ nodeOf)
{
  const int j = blockIdx.x * 256 + threadIdx.x;
  const int f = blockIdx.y;
  if (j < NN) {
    const u64 kk = nodekeys[(size_t)f * SEGN + j];
    const u32 node = (u32)(kk & 0xffffffffu);
    rankOf[(size_t)f * NN + node] = (u32)j;
    nodeOf[(size_t)f * SEGN + j] = node;
  }
}

// ---------------- births + essential deaths ----------------
__global__ __launch_bounds__(256) void init_kernel(
    const float* __restrict__ filt, const u32* __restrict__ maxv,
    float* __restrict__ out)
{
  const int n = blockIdx.x * 256 + threadIdx.x;
  const int f = blockIdx.y;
  if (n < NN) {
    const size_t idx = (size_t)f * NN + n;
    out[idx * 2 + 0] = filt[(size_t)n * 4 + f];
    out[idx * 2 + 1] = decf(maxv[f]);
  }
}

// ---------------- per-edge keys + rank-space endpoints ----------------
__global__ __launch_bounds__(256) void prep_kernel(
    const int* __restrict__ ei, const float* __restrict__ filt,
    const u32* __restrict__ rankOf,
    u32* __restrict__ erank, u64* __restrict__ ekeys)
{
  const int e = blockIdx.x * 256 + threadIdx.x;
  if (e >= NE) return;
  const int s = ei[e];
  const int d = ei[NE + e];
  const float4 vs = *(const float4*)&filt[(size_t)s * 4];
  const float4 vd = *(const float4*)&filt[(size_t)d * 4];
  ekeys[0 * (size_t)NE + e] = ((u64)encf(fmaxf(vs.x, vd.x)) << 32) | (u32)e;
  ekeys[1 * (size_t)NE + e] = ((u64)encf(fmaxf(vs.y, vd.y)) << 32) | (u32)e;
  ekeys[2 * (size_t)NE + e] = ((u64)encf(fmaxf(vs.z, vd.z)) << 32) | (u32)e;
  ekeys[3 * (size_t)NE + e] = ((u64)encf(fmaxf(vs.w, vd.w)) << 32) | (u32)e;
  #pragma unroll
  for (int f = 0; f < 4; f++) {
    const u32 ru = rankOf[(size_t)f * NN + s];
    const u32 rt = rankOf[(size_t)f * NN + d];
    erank[(size_t)f * NE + e] = (ru << 16) | rt;
  }
}

// ---------------- Boruvka round: per-edge min-outgoing-key selection ----------------
__global__ __launch_bounds__(256) void bor_edges(
    const u64* __restrict__ ekeys, const u32* __restrict__ erank,
    const u32* __restrict__ comp, u64* __restrict__ minOut,
    u8* __restrict__ dead, const u32* __restrict__ done)
{
  const int f = blockIdx.y;
  if (done[f]) return;
  const int e = blockIdx.x * 256 + threadIdx.x;
  if (e >= NE) return;
  if (dead[(size_t)f * NE + e]) return;    // settled internal edge: skip all gathers
  const u32 pr = erank[(size_t)f * NE + e];
  const u32* cf = comp + (size_t)f * NN;
  u32 a = cf[pr >> 16]; a = cf[a];
  u32 b = cf[pr & 0xffffu]; b = cf[b];
  if (a == b) { dead[(size_t)f * NE + e] = 1; return; }  // connectivity is monotone
  const u64 k = ekeys[(size_t)f * NE + e];
  atomicMin(&minOut[(size_t)f * NN + a], k);
  atomicMin(&minOut[(size_t)f * NN + b], k);
}

// ---------------- Boruvka round: choose hooks + record MSF edges ----------------
__global__ __launch_bounds__(256) void bor_choose(
    const u32* __restrict__ erank, const u32* __restrict__ comp,
    const u64* __restrict__ minOut, u32* __restrict__ hookTo,
    u64* __restrict__ msf, u32* __restrict__ msfCnt,
    const u32* __restrict__ done, u32* __restrict__ changed)
{
  const int f = blockIdx.y;
  if (done[f]) return;
  const int r = blockIdx.x * 256 + threadIdx.x;
  if (r >= NN) return;
  const u32* cf = comp + (size_t)f * NN;
  if (cf[r] != (u32)r) return;                       // roots only
  const u64 k = minOut[(size_t)f * NN + r];
  if (k == ~0ull) return;                            // isolated component
  const u32 e = (u32)(k & 0xffffffffu);
  const u32 pr = erank[(size_t)f * NE + e];
  u32 a = cf[pr >> 16]; a = cf[a];
  u32 b = cf[pr & 0xffffu]; b = cf[b];
  const u32 other = (a == (u32)r) ? b : a;
  // mutual-min pair: only the larger id hooks (records once); chains otherwise
  // strictly decrease in key along hooks -> acyclic
  if (minOut[(size_t)f * NN + other] == k && other > (u32)r) return;
  hookTo[(size_t)f * NN + r] = other;
  changed[f] = 1u;
  const u32 slot = atomicAdd(&msfCnt[f], 1u);
  msf[(size_t)f * SEGN + slot] = k;
}

// ---------------- Boruvka round: apply hooks (clean snapshot) + done flag ----------------
__global__ __launch_bounds__(256) void bor_apply(
    u32* __restrict__ comp, u32* __restrict__ hookTo,
    u32* __restrict__ done, u32* __restrict__ changed)
{
  const int f = blockIdx.y;
  if (done[f]) return;
  const int r = blockIdx.x * 256 + threadIdx.x;
  if (r >= NN) return;
  const u32 h = hookTo[(size_t)f * NN + r];
  if (h != (u32)r) {
    comp[(size_t)f * NN + r] = h;
    hookTo[(size_t)f * NN + r] = (u32)r;
  }
  if (r == 0) { if (changed[f] == 0u) done[f] = 1u; changed[f] = 0u; }
}

// ---------------- Boruvka round: pointer-jump full compression + minOut reset ----
__global__ __launch_bounds__(256) void bor_jump(
    u32* __restrict__ comp, u64* __restrict__ minOut, const u32* __restrict__ done)
{
  const int f = blockIdx.y;
  if (done[f]) return;
  const int x = blockIdx.x * 256 + threadIdx.x;
  if (x >= NN) return;
  u32* cf = comp + (size_t)f * NN;
  u32 p = cf[x];
  u32 g = cf[p];
  while (p != g) { p = g; g = cf[p]; }   // concurrent writes only shortcut
  cf[x] = p;
  minOut[(size_t)f * NN + x] = ~0ull;
}

// ---------------- bitonic: fused LDS phases k=2..4096 ----------------
__global__ __launch_bounds__(256) void bitonic_lds_full(u64* __restrict__ keys, int seglen)
{
  __shared__ u64 sh[4096];
  u64* a = keys + (size_t)blockIdx.y * seglen + (size_t)blockIdx.x * 4096;
  const int gbase = blockIdx.x * 4096;
  for (int i = threadIdx.x; i < 4096; i += 256) sh[i] = a[i];
  __syncthreads();
  for (int k = 2; k <= 4096; k <<= 1) {
    for (int j = k >> 1; j >= 1; j >>= 1) {
      for (int p = threadIdx.x; p < 2048; p += 256) {
        const int i = ((p & ~(j - 1)) << 1) | (p & (j - 1));
        const int ixj = i + j;
        const bool up = (((gbase + i) & k) == 0);
        const u64 x = sh[i], y = sh[ixj];
        if ((x > y) == up) { sh[i] = y; sh[ixj] = x; }
      }
      __syncthreads();
    }
  }
  for (int i = threadIdx.x; i < 4096; i += 256) a[i] = sh[i];
}

// ---------------- bitonic: fused LDS tail (fixed k, j=2048..1) ----------------
__global__ __launch_bounds__(256) void bitonic_lds_tail(u64* __restrict__ keys, int seglen, int k)
{
  __shared__ u64 sh[4096];
  u64* a = keys + (size_t)blockIdx.y * seglen + (size_t)blockIdx.x * 4096;
  const int gbase = blockIdx.x * 4096;
  for (int i = threadIdx.x; i < 4096; i += 256) sh[i] = a[i];
  __syncthreads();
  for (int j = 2048; j >= 1; j >>= 1) {
    for (int p = threadIdx.x; p < 2048; p += 256) {
      const int i = ((p & ~(j - 1)) << 1) | (p & (j - 1));
      const int ixj = i + j;
      const bool up = (((gbase + i) & k) == 0);
      const u64 x = sh[i], y = sh[ixj];
      if ((x > y) == up) { sh[i] = y; sh[ixj] = x; }
    }
    __syncthreads();
  }
  for (int i = threadIdx.x; i < 4096; i += 256) a[i] = sh[i];
}

// ---------------- bitonic: one global pass (j >= 4096) ----------------
__global__ __launch_bounds__(256) void bitonic_global(u64* __restrict__ keys, int seglen,
                                                      int k, int j)
{
  const int i = blockIdx.x * 256 + threadIdx.x;
  u64* a = keys + (size_t)blockIdx.y * seglen;
  const int ixj = i ^ j;
  if (ixj > i) {
    const u64 x = a[i], y = a[ixj];
    const bool up = ((i & k) == 0);
    if ((x > y) == up) { a[i] = y; a[ixj] = x; }
  }
}

// ---------------- prefix components at partition boundaries (per filtration) ----
// Stage s adds sorted-MSF chunk s-1 into the LDS label array via hook-to-label +
// pointer-jump rounds (benign races; converges when a round changes nothing),
// then dumps snapshot s: lab[x] = min rank of x's component over chunks [0, s).
__global__ __launch_bounds__(1024) void prefixcc_kernel(
    const u64* __restrict__ msf, const u32* __restrict__ msfCnt,
    const u32* __restrict__ erank, u16* __restrict__ snap)
{
  __shared__ u16 lab[NN];      // 100 KB
  __shared__ u32 eL[6272];     // 25 KB: chunk edge endpoint ranks
  __shared__ u32 chg;
  const int f = blockIdx.x;
  const int tid = threadIdx.x;
  const u64* ks = msf + (size_t)f * SEGN;
  const u32* er = erank + (size_t)f * NE;
  const int cnt = (int)msfCnt[f];
  const int C = (cnt + NPART - 1) / NPART;

  u32* lab32 = (u32*)lab;
  for (int j = tid; j < NN / 2; j += 1024)
    lab32[j] = ((u32)(2 * j + 1) << 16) | (u32)(2 * j);
  __syncthreads();

  for (int s = 1; s < NPART; s++) {
    const int lo = (s - 1) * C;
    int hi = s * C; if (hi > cnt) hi = cnt;
    const int len = (hi > lo) ? (hi - lo) : 0;
    for (int i = tid; i < len; i += 1024) {
      const u32 e = (u32)(ks[lo + i] & 0xffffffffu);
      eL[i] = er[e];
    }
    __syncthreads();
    for (int r = 0; r < CCMAXR; r++) {
      if (tid == 0) chg = 0u;
      __syncthreads();
      for (int i = tid; i < len; i += 1024) {
        const u32 pr = eL[i];
        const u32 ra = pr >> 16, rb = pr & 0xffffu;
        const u32 la = lab[ra], lb = lab[rb];
        if (la != lb) {
          const u32 hi2 = la > lb ? la : lb;
          const u32 lo2 = la > lb ? lb : la;
          if (lo2 < (u32)lab[hi2]) { lab[hi2] = (u16)lo2; chg = 1u; }
        }
      }
      for (int x = tid; x < NN; x += 1024) {
        const u32 l0 = lab[x];
        const u32 l1 = lab[l0];
        if (l1 != l0) { lab[x] = (u16)l1; chg = 1u; }
      }
      __syncthreads();
      if (chg == 0u) break;
      __syncthreads();   // protect next round's reset vs this read
    }
    u32* sn32 = (u32*)(snap + ((size_t)f * NPART + s) * NN);
    for (int j = tid; j < NN / 2; j += 1024) sn32[j] = lab32[j];
    __syncthreads();     // eL reused next stage
  }
}

// ---------------- rank-space Kruskal over sorted MSF edges, 8-way partitioned ----
__global__ __launch_bounds__(64) void uf_kernel(
    const u64* __restrict__ msf, const u32* __restrict__ msfCnt,
    const u32* __restrict__ erank, const u32* __restrict__ nodeOf,
    const u16* __restrict__ snap, float* __restrict__ out)
{
  __shared__ u16 par[NN];   // 100 KB LDS
  const int q = blockIdx.x;         // partition
  const int f = blockIdx.y;         // filtration
  const int lane = threadIdx.x;
  const u32* ndOf = nodeOf + (size_t)f * SEGN;
  const u64* ks = msf + (size_t)f * SEGN;
  const u32* er = erank + (size_t)f * NE;
  float* outf = out + (size_t)f * NN * 2;
  const int cnt = (int)msfCnt[f];
  const int C = (cnt + NPART - 1) / NPART;
  const int lo = q * C;
  int hi = lo + C; if (hi > cnt) hi = cnt;

  u32* par32 = (u32*)par;
  if (q == 0) {
    for (int j = lane; j < NN / 2; j += 64)
      par32[j] = ((u32)(2 * j + 1) << 16) | (u32)(2 * j);
  } else {
    const u32* sn32 = (const u32*)(snap + ((size_t)f * NPART + q) * NN);
    for (int j = lane; j < NN / 2; j += 64) par32[j] = sn32[j];
  }
  __syncthreads();
  if (lo >= hi) return;

  u64 key; u32 pr;
  {
    key = ks[lo + lane];
    const u32 e0 = (u32)(key & 0xffffffffu);
    pr = (e0 < (u32)NE) ? er[e0] : 0u;
  }

  for (int base = lo; base < hi; base += 64) {
    u64 nkey = ~0ull;
    if (base + 64 < hi) nkey = ks[base + 64 + lane];

    const bool live = (base + lane < hi);
    int u = 0, t = 0;
    if (live) { u = (int)(pr >> 16); t = (int)(pr & 0xffffu); }

    // dual interleaved path-halving find in LDS (snapshot before batch merges)
    int ru = u, rt = t;
    u32 pu = par[ru], pt = par[rt];
    while (pu != (u32)ru || pt != (u32)rt) {
      const u32 gu = par[pu];
      const u32 gt = par[pt];
      if (pu != (u32)ru) { par[ru] = (u16)gu; ru = (int)gu; }
      if (pt != (u32)rt) { par[rt] = (u16)gt; rt = (int)gt; }
      pu = par[ru]; pt = par[rt];
    }

    u32 npr = 0u;
    if (base + 64 < hi) {
      const u32 ne = (u32)(nkey & 0xffffffffu);
      if (ne < (u32)NE) npr = er[ne];
    }

    // in-order merge resolution: registers + shuffles ONLY
    u64 cand = __ballot(live && (ru != rt));
    int mu = ru, mt = rt;
    int myLose = -1;
    while (cand) {
      const int l = __ffsll((long long)cand) - 1;
      cand &= (cand - 1);
      const int a = __shfl(mu, l);
      const int b = __shfl(mt, l);
      if (a != b) {
        const int win = (a < b) ? a : b;
        const int lose = (a < b) ? b : a;
        if (lane == l) {
          par[lose] = (u16)win;
          myLose = lose;
        }
        mu = (mu == lose) ? win : mu;
        mt = (mt == lose) ? win : mt;
      }
    }

    // parallel epilogue: one vmcnt stall per batch, unique writer per slot
    if (myLose >= 0) {
      const u32 node = ndOf[myLose];
      outf[(size_t)node * 2 + 1] = decf((u32)(key >> 32));
    }

    asm volatile("s_waitcnt lgkmcnt(0)" ::: "memory");
    __builtin_amdgcn_sched_barrier(0);
    key = nkey; pr = npr;
  }
}

extern "C" void kernel_launch(void* const* d_in, const int* in_sizes, int n_in,
                              void* d_out, int out_size, void* d_ws, size_t ws_size,
                              hipStream_t stream)
{
  const float* X  = (const float*)d_in[0];
  const float* W1 = (const float*)d_in[1];
  const float* b1 = (const float*)d_in[2];
  const float* W2 = (const float*)d_in[3];
  const float* b2 = (const float*)d_in[4];
  const int*   EI = (const int*)d_in[5];   // int32 per harness contract
  float* out = (float*)d_out;

  char* w = (char*)d_ws;
  u64*  ekeys    = (u64*)w;   w += (size_t)4 * NE * sizeof(u64);      // 6.4 MB
  u64*  nodekeys = (u64*)w;   w += (size_t)4 * SEGN * sizeof(u64);    // 2 MB
  u64*  minOut   = (u64*)w;   w += (size_t)4 * NN * sizeof(u64);      // 1.6 MB
  u64*  msf      = (u64*)w;   w += (size_t)4 * SEGN * sizeof(u64);    // 2 MB
  float* filt    = (float*)w; w += (size_t)NN * 4 * sizeof(float);    // 0.8 MB
  u32*  rankOf   = (u32*)w;   w += (size_t)4 * NN * sizeof(u32);      // 0.8 MB
  u32*  nodeOf   = (u32*)w;   w += (size_t)4 * SEGN * sizeof(u32);    // 1 MB
  u32*  erank    = (u32*)w;   w += (size_t)4 * NE * sizeof(u32);      // 3.2 MB
  u32*  comp     = (u32*)w;   w += (size_t)4 * NN * sizeof(u32);      // 0.8 MB
  u32*  hookTo   = (u32*)w;   w += (size_t)4 * NN * sizeof(u32);      // 0.8 MB
  u8*   dead     = (u8*)w;    w += (size_t)4 * NE * sizeof(u8);       // 0.8 MB
  u32*  msfCnt   = (u32*)w;   w += 4 * sizeof(u32);
  u32*  done     = (u32*)w;   w += 4 * sizeof(u32);
  u32*  changed  = (u32*)w;   w += 4 * sizeof(u32);
  u32*  maxv     = (u32*)w;   w += 4 * sizeof(u32);

  // snap aliases ekeys (dead after Boruvka; rewritten by prep_kernel each call):
  // 4 filt x NPART x NN u16 = 3.2 MB <= 6.4 MB
  u16* snap = (u16*)ekeys;

  const size_t need = (size_t)(w - (char*)d_ws);
  if (ws_size < need) return;

  const int nodeBlocks = (NN + 255) / 256;
  const int edgeBlocks = (NE + 255) / 256;

  setup_kernel<<<dim3(SEGN / 256, 4), dim3(256), 0, stream>>>(
      msf, comp, minOut, hookTo, dead, msfCnt, done, changed, maxv);
  mlp_kernel<<<dim3((NN + 63) / 64), dim3(256), 0, stream>>>(X, W1, b1, W2, b2, filt);
  maxv_kernel<<<dim3(nodeBlocks, 1), dim3(256), 0, stream>>>(filt, maxv);
  nodeprep_kernel<<<dim3(SEGN / 256, 4), dim3(256), 0, stream>>>(filt, nodekeys);

  // node sort (4 segments of SEGN): rank space
  bitonic_lds_full<<<dim3(SEGN / 4096, 4), dim3(256), 0, stream>>>(nodekeys, SEGN);
  for (int k = 8192; k <= SEGN; k <<= 1) {
    for (int j = k >> 1; j >= 4096; j >>= 1)
      bitonic_global<<<dim3(SEGN / 256, 4), dim3(256), 0, stream>>>(nodekeys, SEGN, k, j);
    bitonic_lds_tail<<<dim3(SEGN / 4096, 4), dim3(256), 0, stream>>>(nodekeys, SEGN, k);
  }

  rank_kernel<<<dim3(SEGN / 256, 4), dim3(256), 0, stream>>>(nodekeys, rankOf, nodeOf);
  init_kernel<<<dim3(nodeBlocks, 4), dim3(256), 0, stream>>>(filt, maxv, out);
  prep_kernel<<<dim3(edgeBlocks, 1), dim3(256), 0, stream>>>(EI, filt, rankOf, erank, ekeys);

  // Boruvka MSF (parallel); done-flag turns converged rounds into no-ops
  for (int r = 0; r < BOR_ROUNDS; r++) {
    bor_edges<<<dim3(edgeBlocks, 4), dim3(256), 0, stream>>>(ekeys, erank, comp, minOut,
                                                             dead, done);
    bor_choose<<<dim3(nodeBlocks, 4), dim3(256), 0, stream>>>(erank, comp, minOut, hookTo,
                                                              msf, msfCnt, done, changed);
    bor_apply<<<dim3(nodeBlocks, 4), dim3(256), 0, stream>>>(comp, hookTo, done, changed);
    bor_jump<<<dim3(nodeBlocks, 4), dim3(256), 0, stream>>>(comp, minOut, done);
  }

  // sort MSF keys (4 segments of SEGN; ~0ull padding sorts to the end)
  bitonic_lds_full<<<dim3(SEGN / 4096, 4), dim3(256), 0, stream>>>(msf, SEGN);
  for (int k = 8192; k <= SEGN; k <<= 1) {
    for (int j = k >> 1; j >= 4096; j >>= 1)
      bitonic_global<<<dim3(SEGN / 256, 4), dim3(256), 0, stream>>>(msf, SEGN, k, j);
    bitonic_lds_tail<<<dim3(SEGN / 4096, 4), dim3(256), 0, stream>>>(msf, SEGN, k);
  }

  // prefix components at partition boundaries (reads sorted msf; writes snap)
  prefixcc_kernel<<<dim3(4), dim3(1024), 0, stream>>>(msf, msfCnt, erank, snap);

  // partitioned serial scans: 8 partitions x 4 filtrations
  uf_kernel<<<dim3(NPART, 4), dim3(64), 0, stream>>>(msf, msfCnt, erank, nodeOf, snap, out);
}

// Round 8
// 3064.186 us; speedup vs baseline: 31.0674x; 1.6815x over previous
//
#include <hip/hip_runtime.h>
#include <stdint.h>

#define NN 50000
#define NE 200000
#define NFEAT 512
#define NHID 256
#define SEG 262144   /* 2^18 >= NE: edge sort segment */
#define SEGN 65536   /* 2^16 >= NN: node sort segment */
#define NPART 16     /* partitions of the sorted-edge Kruskal scan */
#define PIECE 12500  /* prefixcc LDS edge-piece size */
#define CCMAXR 64    /* max hook+jump rounds per prefix-CC piece */

typedef unsigned long long u64;
typedef unsigned int u32;
typedef unsigned short u16;

// cost-balanced partition boundaries over the sorted 200k edges
// (equalize: batches*0.33us + expected_merges*0.08us; merge profile of the
// filtration process M(i) ~ k - comp(ER(k, k/6250)), k = 50000*sqrt(i/2e5))
__device__ const int PB[NPART + 1] = {
    0, 3840, 9280, 15168, 21760, 28480, 37504, 46528, 62784,
    75840, 91200, 106944, 124032, 141824, 160448, 180224, 200000};

// order-preserving float -> u32 (strictly monotone), exact round-trip
__device__ __forceinline__ u32 encf(float x) {
  u32 u = __float_as_uint(x);
  return (u & 0x80000000u) ? ~u : (u | 0x80000000u);
}
__device__ __forceinline__ float decf(u32 y) {
  u32 u = (y & 0x80000000u) ? (y ^ 0x80000000u) : ~y;
  return __uint_as_float(u);
}

#define SWZ(c) ((c) ^ ((((c) >> 5) & 7) << 2))

// ---------------- filt = relu(X@W1 + b1) @ W2 + b2  -> (NN x 4) f32 ----------------
__global__ __launch_bounds__(256) void mlp_kernel(
    const float* __restrict__ X, const float* __restrict__ W1,
    const float* __restrict__ b1, const float* __restrict__ W2,
    const float* __restrict__ b2, float* __restrict__ filt)
{
  __shared__ float As[64][33];
  __shared__ float Ws[32][256];
  __shared__ float W2s[256][4];

  const int tid = threadIdx.x;
  const int row0 = blockIdx.x * 64;
  const int tr = tid >> 4, tc = tid & 15;

  for (int i = tid; i < NHID * 4; i += 256) W2s[i >> 2][i & 3] = W2[i];

  float4 acc[4][4];
  #pragma unroll
  for (int i = 0; i < 4; i++)
    #pragma unroll
    for (int q = 0; q < 4; q++) acc[i][q] = make_float4(0.f, 0.f, 0.f, 0.f);

  for (int k0 = 0; k0 < NFEAT; k0 += 32) {
    __syncthreads();
    {
      const int r = tid >> 3, c4 = (tid & 7) << 2;
      #pragma unroll
      for (int rr = 0; rr < 2; rr++) {
        const int row = r + rr * 32;
        const int grow = row0 + row;
        float4 v = make_float4(0.f, 0.f, 0.f, 0.f);
        if (grow < NN) v = *(const float4*)&X[(size_t)grow * NFEAT + k0 + c4];
        As[row][c4 + 0] = v.x; As[row][c4 + 1] = v.y;
        As[row][c4 + 2] = v.z; As[row][c4 + 3] = v.w;
      }
      const int wr = tid >> 6, wc4 = (tid & 63) << 2;
      const int pc = SWZ(wc4);
      #pragma unroll
      for (int rr = 0; rr < 8; rr++) {
        const int rowk = wr + rr * 4;
        float4 v = *(const float4*)&W1[(size_t)(k0 + rowk) * NHID + wc4];
        *(float4*)&Ws[rowk][pc] = v;
      }
    }
    __syncthreads();
    #pragma unroll 8
    for (int kk = 0; kk < 32; kk++) {
      const float a0 = As[tr * 4 + 0][kk], a1 = As[tr * 4 + 1][kk],
                  a2 = As[tr * 4 + 2][kk], a3 = As[tr * 4 + 3][kk];
      #pragma unroll
      for (int q = 0; q < 4; q++) {
        const int col = tc * 16 + q * 4;
        const float4 wv = *(const float4*)&Ws[kk][SWZ(col)];
        acc[0][q].x += a0 * wv.x; acc[0][q].y += a0 * wv.y;
        acc[0][q].z += a0 * wv.z; acc[0][q].w += a0 * wv.w;
        acc[1][q].x += a1 * wv.x; acc[1][q].y += a1 * wv.y;
        acc[1][q].z += a1 * wv.z; acc[1][q].w += a1 * wv.w;
        acc[2][q].x += a2 * wv.x; acc[2][q].y += a2 * wv.y;
        acc[2][q].z += a2 * wv.z; acc[2][q].w += a2 * wv.w;
        acc[3][q].x += a3 * wv.x; acc[3][q].y += a3 * wv.y;
        acc[3][q].w += a3 * wv.w; acc[3][q].z += a3 * wv.z;
      }
    }
  }

  float p[4][4];
  #pragma unroll
  for (int i = 0; i < 4; i++)
    #pragma unroll
    for (int f = 0; f < 4; f++) p[i][f] = 0.f;

  #pragma unroll
  for (int q = 0; q < 4; q++) {
    const int colb = tc * 16 + q * 4;
    float bb[4];
    #pragma unroll
    for (int j = 0; j < 4; j++) bb[j] = b1[colb + j];
    #pragma unroll
    for (int i = 0; i < 4; i++) {
      float h[4] = {acc[i][q].x + bb[0], acc[i][q].y + bb[1],
                    acc[i][q].z + bb[2], acc[i][q].w + bb[3]};
      #pragma unroll
      for (int j = 0; j < 4; j++) {
        const float hh = fmaxf(h[j], 0.f);
        #pragma unroll
        for (int f = 0; f < 4; f++) p[i][f] += hh * W2s[colb + j][f];
      }
    }
  }

  #pragma unroll
  for (int m = 1; m < 16; m <<= 1)
    #pragma unroll
    for (int i = 0; i < 4; i++)
      #pragma unroll
      for (int f = 0; f < 4; f++)
        p[i][f] += __shfl_xor(p[i][f], m, 64);

  if (tc == 0) {
    const float c0 = b2[0], c1 = b2[1], c2 = b2[2], c3 = b2[3];
    #pragma unroll
    for (int i = 0; i < 4; i++) {
      const int row = row0 + tr * 4 + i;
      if (row < NN) {
        float4 o = make_float4(p[i][0] + c0, p[i][1] + c1, p[i][2] + c2, p[i][3] + c3);
        *(float4*)&filt[(size_t)row * 4] = o;
      }
    }
  }
}

__global__ void zero4_kernel(u32* __restrict__ maxv) {
  if (threadIdx.x < 4) maxv[threadIdx.x] = 0u;
}

__global__ __launch_bounds__(256) void maxv_kernel(const float* __restrict__ filt,
                                                   u32* __restrict__ maxv)
{
  __shared__ u32 lm[4];
  if (threadIdx.x < 4) lm[threadIdx.x] = 0u;
  __syncthreads();
  const int n = blockIdx.x * 256 + threadIdx.x;
  if (n < NN) {
    const float4 v = *(const float4*)&filt[(size_t)n * 4];
    atomicMax(&lm[0], encf(v.x));
    atomicMax(&lm[1], encf(v.y));
    atomicMax(&lm[2], encf(v.z));
    atomicMax(&lm[3], encf(v.w));
  }
  __syncthreads();
  if (threadIdx.x < 4) atomicMax(&maxv[threadIdx.x], lm[threadIdx.x]);
}

// ---------------- node sort keys: (enc(v), node), padded ----------------
__global__ __launch_bounds__(256) void nodeprep_kernel(const float* __restrict__ filt,
                                                       u64* __restrict__ nodekeys)
{
  const int n = blockIdx.x * 256 + threadIdx.x;
  const int f = blockIdx.y;
  if (n < NN) {
    const float v = filt[(size_t)n * 4 + f];
    nodekeys[(size_t)f * SEGN + n] = ((u64)encf(v) << 32) | (u32)n;
  } else if (n < SEGN) {
    nodekeys[(size_t)f * SEGN + n] = ~0ull;
  }
}

// ---------------- rank scatter ----------------
__global__ __launch_bounds__(256) void rank_kernel(const u64* __restrict__ nodekeys,
                                                   u32* __restrict__ rankOf,
                                                   u32* __restrict__ nodeOf)
{
  const int j = blockIdx.x * 256 + threadIdx.x;
  const int f = blockIdx.y;
  if (j < NN) {
    const u64 kk = nodekeys[(size_t)f * SEGN + j];
    const u32 node = (u32)(kk & 0xffffffffu);
    rankOf[(size_t)f * NN + node] = (u32)j;
    nodeOf[(size_t)f * SEGN + j] = node;
  }
}

// ---------------- births + essential deaths ----------------
__global__ __launch_bounds__(256) void init_kernel(
    const float* __restrict__ filt, const u32* __restrict__ maxv,
    float* __restrict__ out)
{
  const int n = blockIdx.x * 256 + threadIdx.x;
  const int f = blockIdx.y;
  if (n < NN) {
    const size_t idx = (size_t)f * NN + n;
    out[idx * 2 + 0] = filt[(size_t)n * 4 + f];
    out[idx * 2 + 1] = decf(maxv[f]);
  }
}

// ---------------- per-edge sort keys (padded) + rank-space endpoints ----------------
__global__ __launch_bounds__(256) void prep_kernel(
    const int* __restrict__ ei, const float* __restrict__ filt,
    const u32* __restrict__ rankOf,
    u32* __restrict__ erank, u64* __restrict__ skeys)
{
  const int e = blockIdx.x * 256 + threadIdx.x;
  if (e < NE) {
    const int s = ei[e];
    const int d = ei[NE + e];
    const float4 vs = *(const float4*)&filt[(size_t)s * 4];
    const float4 vd = *(const float4*)&filt[(size_t)d * 4];
    skeys[0 * (size_t)SEG + e] = ((u64)encf(fmaxf(vs.x, vd.x)) << 32) | (u32)e;
    skeys[1 * (size_t)SEG + e] = ((u64)encf(fmaxf(vs.y, vd.y)) << 32) | (u32)e;
    skeys[2 * (size_t)SEG + e] = ((u64)encf(fmaxf(vs.z, vd.z)) << 32) | (u32)e;
    skeys[3 * (size_t)SEG + e] = ((u64)encf(fmaxf(vs.w, vd.w)) << 32) | (u32)e;
    #pragma unroll
    for (int f = 0; f < 4; f++) {
      const u32 ru = rankOf[(size_t)f * NN + s];
      const u32 rt = rankOf[(size_t)f * NN + d];
      erank[(size_t)f * NE + e] = (ru << 16) | rt;
    }
  } else if (e < SEG) {
    skeys[0 * (size_t)SEG + e] = ~0ull; skeys[1 * (size_t)SEG + e] = ~0ull;
    skeys[2 * (size_t)SEG + e] = ~0ull; skeys[3 * (size_t)SEG + e] = ~0ull;
  }
}

// ---------------- bitonic: fused LDS phases k=2..4096 ----------------
__global__ __launch_bounds__(256) void bitonic_lds_full(u64* __restrict__ keys, int seglen)
{
  __shared__ u64 sh[4096];
  u64* a = keys + (size_t)blockIdx.y * seglen + (size_t)blockIdx.x * 4096;
  const int gbase = blockIdx.x * 4096;
  for (int i = threadIdx.x; i < 4096; i += 256) sh[i] = a[i];
  __syncthreads();
  for (int k = 2; k <= 4096; k <<= 1) {
    for (int j = k >> 1; j >= 1; j >>= 1) {
      for (int p = threadIdx.x; p < 2048; p += 256) {
        const int i = ((p & ~(j - 1)) << 1) | (p & (j - 1));
        const int ixj = i + j;
        const bool up = (((gbase + i) & k) == 0);
        const u64 x = sh[i], y = sh[ixj];
        if ((x > y) == up) { sh[i] = y; sh[ixj] = x; }
      }
      __syncthreads();
    }
  }
  for (int i = threadIdx.x; i < 4096; i += 256) a[i] = sh[i];
}

// ---------------- bitonic: fused LDS tail (fixed k, j=2048..1) ----------------
__global__ __launch_bounds__(256) void bitonic_lds_tail(u64* __restrict__ keys, int seglen, int k)
{
  __shared__ u64 sh[4096];
  u64* a = keys + (size_t)blockIdx.y * seglen + (size_t)blockIdx.x * 4096;
  const int gbase = blockIdx.x * 4096;
  for (int i = threadIdx.x; i < 4096; i += 256) sh[i] = a[i];
  __syncthreads();
  for (int j = 2048; j >= 1; j >>= 1) {
    for (int p = threadIdx.x; p < 2048; p += 256) {
      const int i = ((p & ~(j - 1)) << 1) | (p & (j - 1));
      const int ixj = i + j;
      const bool up = (((gbase + i) & k) == 0);
      const u64 x = sh[i], y = sh[ixj];
      if ((x > y) == up) { sh[i] = y; sh[ixj] = x; }
    }
    __syncthreads();
  }
  for (int i = threadIdx.x; i < 4096; i += 256) a[i] = sh[i];
}

// ---------------- bitonic: one global pass (j >= 4096) ----------------
__global__ __launch_bounds__(256) void bitonic_global(u64* __restrict__ keys, int seglen,
                                                      int k, int j)
{
  const int i = blockIdx.x * 256 + threadIdx.x;
  u64* a = keys + (size_t)blockIdx.y * seglen;
  const int ixj = i ^ j;
  if (ixj > i) {
    const u64 x = a[i], y = a[ixj];
    const bool up = ((i & k) == 0);
    if ((x > y) == up) { a[i] = y; a[ixj] = x; }
  }
}

// ---------------- prefix components at partition boundaries (per filtration) ----
// Stage s adds edges [PB[s-1], PB[s]) to the LDS label forest (in LDS pieces)
// via hook-to-min + pointer-jump rounds (benign races; converge per piece),
// then dumps snapshot s: lab[x] = min rank of x's component over edges [0,PB[s]).
__global__ __launch_bounds__(1024) void prefixcc_kernel(
    const u64* __restrict__ skeys, const u32* __restrict__ erank,
    u16* __restrict__ snap)
{
  __shared__ u16 lab[NN];      // 100 KB
  __shared__ u32 eL[PIECE];    // 50 KB
  __shared__ u32 chg;
  const int f = blockIdx.x;
  const int tid = threadIdx.x;
  const u64* ks = skeys + (size_t)f * SEG;
  const u32* er = erank + (size_t)f * NE;

  u32* lab32 = (u32*)lab;
  for (int j = tid; j < NN / 2; j += 1024)
    lab32[j] = ((u32)(2 * j + 1) << 16) | (u32)(2 * j);
  __syncthreads();

  for (int s = 1; s < NPART; s++) {
    const int lo = PB[s - 1], hi = PB[s];
    for (int plo = lo; plo < hi; plo += PIECE) {
      int phi = plo + PIECE; if (phi > hi) phi = hi;
      const int len = phi - plo;
      for (int i = tid; i < len; i += 1024)
        eL[i] = er[(u32)(ks[plo + i] & 0xffffffffu)];
      __syncthreads();
      for (int r = 0; r < CCMAXR; r++) {
        if (tid == 0) chg = 0u;
        __syncthreads();
        for (int i = tid; i < len; i += 1024) {
          const u32 pr = eL[i];
          const u32 la = lab[pr >> 16], lb = lab[pr & 0xffffu];
          if (la != lb) {
            const u32 h = la > lb ? la : lb;
            const u32 l2 = la ^ lb ^ h;
            if (l2 < (u32)lab[h]) { lab[h] = (u16)l2; chg = 1u; }
          }
        }
        for (int x = tid; x < NN; x += 1024) {
          const u32 l0 = lab[x];
          const u32 l1 = lab[l0];
          if (l1 != l0) { lab[x] = (u16)l1; chg = 1u; }
        }
        __syncthreads();
        if (chg == 0u) break;
        __syncthreads();
      }
    }
    u32* sn32 = (u32*)(snap + ((size_t)f * NPART + s) * NN);
    for (int j = tid; j < NN / 2; j += 1024) sn32[j] = lab32[j];
  }
}

// ---------------- rank-space Kruskal over all sorted edges, 16-way partitioned ----
__global__ __launch_bounds__(512) void uf_kernel(
    const u64* __restrict__ skeys, const u32* __restrict__ erank,
    const u32* __restrict__ nodeOf, const u16* __restrict__ snap,
    float* __restrict__ out)
{
  __shared__ __align__(16) u16 par[NN];   // 100 KB
  const int q = blockIdx.x;               // partition
  const int f = blockIdx.y;               // filtration
  const int tid = threadIdx.x;

  // all 8 waves: vectorized parent init / snapshot load
  if (q == 0) {
    u32* par32 = (u32*)par;
    for (int j = tid; j < NN / 2; j += 512)
      par32[j] = ((u32)(2 * j + 1) << 16) | (u32)(2 * j);
  } else {
    const uint4* sn = (const uint4*)(snap + ((size_t)f * NPART + q) * NN);
    uint4* p4 = (uint4*)par;
    for (int j = tid; j < NN / 8; j += 512) p4[j] = sn[j];   // NN*2/16 = 6250
  }
  __syncthreads();
  if (tid >= 64) return;   // wave 0 runs the scan
  const int lane = tid;

  const u64* ks = skeys + (size_t)f * SEG;
  const u32* er = erank + (size_t)f * NE;
  const u32* ndOf = nodeOf + (size_t)f * SEGN;
  float* outf = out + (size_t)f * NN * 2;
  const int lo = PB[q], hi = PB[q + 1];

  u64 key = ks[lo + lane];
  u32 pr;
  { const u32 e0 = (u32)(key & 0xffffffffu); pr = (e0 < (u32)NE) ? er[e0] : 0u; }

  for (int base = lo; base < hi; base += 64) {
    u64 nkey = ~0ull;
    if (base + 64 < hi) nkey = ks[base + 64 + lane];

    const bool live = (base + lane < hi);
    int u = 0, t = 0;
    if (live) { u = (int)(pr >> 16); t = (int)(pr & 0xffffu); }

    // dual interleaved path-halving find in LDS (snapshot before batch merges)
    int ru = u, rt = t;
    u32 pu = par[ru], pt = par[rt];
    while (pu != (u32)ru || pt != (u32)rt) {
      const u32 gu = par[pu];
      const u32 gt = par[pt];
      if (pu != (u32)ru) { par[ru] = (u16)gu; ru = (int)gu; }
      if (pt != (u32)rt) { par[rt] = (u16)gt; rt = (int)gt; }
      pu = par[ru]; pt = par[rt];
    }

    u32 npr = 0u;
    if (base + 64 < hi) {
      const u32 ne = (u32)(nkey & 0xffffffffu);
      if (ne < (u32)NE) npr = er[ne];
    }

    // in-order merge resolution: ONE packed shuffle per step (ranks < 2^16)
    u64 cand = __ballot(live && (ru != rt));
    u32 mp = ((u32)ru << 16) | (u32)rt;
    int myLose = -1;
    while (cand) {
      const int l = __ffsll((long long)cand) - 1;
      cand &= (cand - 1);
      const u32 ab = (u32)__shfl((int)mp, l);
      const u32 a = ab >> 16, b = ab & 0xffffu;
      if (a != b) {
        const u32 win = a < b ? a : b;
        const u32 lose = a ^ b ^ win;
        if (lane == l) { par[lose] = (u16)win; myLose = (int)lose; }
        const u32 h2 = mp >> 16, l2 = mp & 0xffffu;
        mp = ((h2 == lose ? win : h2) << 16) | (l2 == lose ? win : l2);
      }
    }

    // parallel epilogue: one vmcnt stall per batch, unique writer per slot
    if (myLose >= 0) {
      const u32 node = ndOf[myLose];
      outf[(size_t)node * 2 + 1] = decf((u32)(key >> 32));
    }

    asm volatile("s_waitcnt lgkmcnt(0)" ::: "memory");
    __builtin_amdgcn_sched_barrier(0);
    key = nkey; pr = npr;
  }
}

extern "C" void kernel_launch(void* const* d_in, const int* in_sizes, int n_in,
                              void* d_out, int out_size, void* d_ws, size_t ws_size,
                              hipStream_t stream)
{
  const float* X  = (const float*)d_in[0];
  const float* W1 = (const float*)d_in[1];
  const float* b1 = (const float*)d_in[2];
  const float* W2 = (const float*)d_in[3];
  const float* b2 = (const float*)d_in[4];
  const int*   EI = (const int*)d_in[5];   // int32 per harness contract
  float* out = (float*)d_out;

  char* w = (char*)d_ws;
  u64*  skeys  = (u64*)w;   w += (size_t)4 * SEG * sizeof(u64);          // 8,388,608
  u16*  snap   = (u16*)w;   w += (size_t)NPART * 4 * NN * sizeof(u16);   // 6,400,000
  u32*  erank  = (u32*)w;   w += (size_t)4 * NE * sizeof(u32);           // 3,200,000
  float* filt  = (float*)w; w += (size_t)NN * 4 * sizeof(float);         //   800,000
  u32*  rankOf = (u32*)w;   w += (size_t)4 * NN * sizeof(u32);           //   800,000
  u32*  nodeOf = (u32*)w;   w += (size_t)4 * SEGN * sizeof(u32);         // 1,048,576
  u32*  maxv   = (u32*)w;   w += 4 * sizeof(u32);

  // nodekeys aliases the snap region (nodekeys is dead before prefixcc writes snap)
  u64* nodekeys = (u64*)snap;   // 4*SEGN*8 = 2,097,152 <= 6,400,000

  const size_t need = (size_t)(w - (char*)d_ws);
  if (ws_size < need) return;

  const int nodeBlocks = (NN + 255) / 256;

  zero4_kernel<<<dim3(1), dim3(64), 0, stream>>>(maxv);
  mlp_kernel<<<dim3((NN + 63) / 64), dim3(256), 0, stream>>>(X, W1, b1, W2, b2, filt);
  maxv_kernel<<<dim3(nodeBlocks, 1), dim3(256), 0, stream>>>(filt, maxv);
  nodeprep_kernel<<<dim3(SEGN / 256, 4), dim3(256), 0, stream>>>(filt, nodekeys);

  // node sort (4 segments of SEGN): rank space
  bitonic_lds_full<<<dim3(SEGN / 4096, 4), dim3(256), 0, stream>>>(nodekeys, SEGN);
  for (int k = 8192; k <= SEGN; k <<= 1) {
    for (int j = k >> 1; j >= 4096; j >>= 1)
      bitonic_global<<<dim3(SEGN / 256, 4), dim3(256), 0, stream>>>(nodekeys, SEGN, k, j);
    bitonic_lds_tail<<<dim3(SEGN / 4096, 4), dim3(256), 0, stream>>>(nodekeys, SEGN, k);
  }

  rank_kernel<<<dim3(SEGN / 256, 4), dim3(256), 0, stream>>>(nodekeys, rankOf, nodeOf);
  init_kernel<<<dim3(nodeBlocks, 4), dim3(256), 0, stream>>>(filt, maxv, out);
  prep_kernel<<<dim3(SEG / 256, 1), dim3(256), 0, stream>>>(EI, filt, rankOf, erank, skeys);

  // edge sort (4 segments of SEG; ~0ull padding sorts to the end)
  bitonic_lds_full<<<dim3(SEG / 4096, 4), dim3(256), 0, stream>>>(skeys, SEG);
  for (int k = 8192; k <= SEG; k <<= 1) {
    for (int j = k >> 1; j >= 4096; j >>= 1)
      bitonic_global<<<dim3(SEG / 256, 4), dim3(256), 0, stream>>>(skeys, SEG, k, j);
    bitonic_lds_tail<<<dim3(SEG / 4096, 4), dim3(256), 0, stream>>>(skeys, SEG, k);
  }

  // prefix components at partition boundaries (writes snap; overwrites nodekeys alias)
  prefixcc_kernel<<<dim3(4), dim3(1024), 0, stream>>>(skeys, erank, snap);

  // partitioned serial scans: 16 cost-balanced partitions x 4 filtrations
  uf_kernel<<<dim3(NPART, 4), dim3(512), 0, stream>>>(skeys, erank, nodeOf, snap, out);
}

// Round 9
// 2338.047 us; speedup vs baseline: 40.7162x; 1.3106x over previous
//
#include <hip/hip_runtime.h>
#include <stdint.h>

#define NN 50000
#define NE 200000
#define NFEAT 512
#define NHID 256
#define SEG 262144   /* 2^18 >= NE: edge sort segment */
#define SEGN 65536   /* 2^16 >= NN: node sort segment */
#define NPART 16     /* partitions of the sorted-edge Kruskal scan */
#define PIECE 12500  /* prefixcc LDS edge-piece size */
#define CCMAXR 64    /* max hook+jump rounds per prefix-CC piece */

typedef unsigned long long u64;
typedef unsigned int u32;
typedef unsigned short u16;

// cost-balanced partition boundaries over the sorted 200k edges.
// cost/edge = 6.25ns (batch base) + 30ns * merge_density(i); density from the
// growing-ER filtration process k(i)=N*sqrt(i/E) (node influx keeps the tail
// density ~0.13, front ~0.9). All boundaries multiples of 64.
__device__ const int PB[NPART + 1] = {
    0, 5184, 10496, 18048, 26944, 37760, 48896, 61760, 74816,
    88960, 103488, 118464, 134208, 149952, 166528, 183296, 200000};

// order-preserving float -> u32 (strictly monotone), exact round-trip
__device__ __forceinline__ u32 encf(float x) {
  u32 u = __float_as_uint(x);
  return (u & 0x80000000u) ? ~u : (u | 0x80000000u);
}
__device__ __forceinline__ float decf(u32 y) {
  u32 u = (y & 0x80000000u) ? (y ^ 0x80000000u) : ~y;
  return __uint_as_float(u);
}

#define SWZ(c) ((c) ^ ((((c) >> 5) & 7) << 2))

// ---------------- filt = relu(X@W1 + b1) @ W2 + b2  -> (NN x 4) f32 ----------------
__global__ __launch_bounds__(256) void mlp_kernel(
    const float* __restrict__ X, const float* __restrict__ W1,
    const float* __restrict__ b1, const float* __restrict__ W2,
    const float* __restrict__ b2, float* __restrict__ filt)
{
  __shared__ float As[64][33];
  __shared__ float Ws[32][256];
  __shared__ float W2s[256][4];

  const int tid = threadIdx.x;
  const int row0 = blockIdx.x * 64;
  const int tr = tid >> 4, tc = tid & 15;

  for (int i = tid; i < NHID * 4; i += 256) W2s[i >> 2][i & 3] = W2[i];

  float4 acc[4][4];
  #pragma unroll
  for (int i = 0; i < 4; i++)
    #pragma unroll
    for (int q = 0; q < 4; q++) acc[i][q] = make_float4(0.f, 0.f, 0.f, 0.f);

  for (int k0 = 0; k0 < NFEAT; k0 += 32) {
    __syncthreads();
    {
      const int r = tid >> 3, c4 = (tid & 7) << 2;
      #pragma unroll
      for (int rr = 0; rr < 2; rr++) {
        const int row = r + rr * 32;
        const int grow = row0 + row;
        float4 v = make_float4(0.f, 0.f, 0.f, 0.f);
        if (grow < NN) v = *(const float4*)&X[(size_t)grow * NFEAT + k0 + c4];
        As[row][c4 + 0] = v.x; As[row][c4 + 1] = v.y;
        As[row][c4 + 2] = v.z; As[row][c4 + 3] = v.w;
      }
      const int wr = tid >> 6, wc4 = (tid & 63) << 2;
      const int pc = SWZ(wc4);
      #pragma unroll
      for (int rr = 0; rr < 8; rr++) {
        const int rowk = wr + rr * 4;
        float4 v = *(const float4*)&W1[(size_t)(k0 + rowk) * NHID + wc4];
        *(float4*)&Ws[rowk][pc] = v;
      }
    }
    __syncthreads();
    #pragma unroll 8
    for (int kk = 0; kk < 32; kk++) {
      const float a0 = As[tr * 4 + 0][kk], a1 = As[tr * 4 + 1][kk],
                  a2 = As[tr * 4 + 2][kk], a3 = As[tr * 4 + 3][kk];
      #pragma unroll
      for (int q = 0; q < 4; q++) {
        const int col = tc * 16 + q * 4;
        const float4 wv = *(const float4*)&Ws[kk][SWZ(col)];
        acc[0][q].x += a0 * wv.x; acc[0][q].y += a0 * wv.y;
        acc[0][q].z += a0 * wv.z; acc[0][q].w += a0 * wv.w;
        acc[1][q].x += a1 * wv.x; acc[1][q].y += a1 * wv.y;
        acc[1][q].z += a1 * wv.z; acc[1][q].w += a1 * wv.w;
        acc[2][q].x += a2 * wv.x; acc[2][q].y += a2 * wv.y;
        acc[2][q].z += a2 * wv.z; acc[2][q].w += a2 * wv.w;
        acc[3][q].x += a3 * wv.x; acc[3][q].y += a3 * wv.y;
        acc[3][q].w += a3 * wv.w; acc[3][q].z += a3 * wv.z;
      }
    }
  }

  float p[4][4];
  #pragma unroll
  for (int i = 0; i < 4; i++)
    #pragma unroll
    for (int f = 0; f < 4; f++) p[i][f] = 0.f;

  #pragma unroll
  for (int q = 0; q < 4; q++) {
    const int colb = tc * 16 + q * 4;
    float bb[4];
    #pragma unroll
    for (int j = 0; j < 4; j++) bb[j] = b1[colb + j];
    #pragma unroll
    for (int i = 0; i < 4; i++) {
      float h[4] = {acc[i][q].x + bb[0], acc[i][q].y + bb[1],
                    acc[i][q].z + bb[2], acc[i][q].w + bb[3]};
      #pragma unroll
      for (int j = 0; j < 4; j++) {
        const float hh = fmaxf(h[j], 0.f);
        #pragma unroll
        for (int f = 0; f < 4; f++) p[i][f] += hh * W2s[colb + j][f];
      }
    }
  }

  #pragma unroll
  for (int m = 1; m < 16; m <<= 1)
    #pragma unroll
    for (int i = 0; i < 4; i++)
      #pragma unroll
      for (int f = 0; f < 4; f++)
        p[i][f] += __shfl_xor(p[i][f], m, 64);

  if (tc == 0) {
    const float c0 = b2[0], c1 = b2[1], c2 = b2[2], c3 = b2[3];
    #pragma unroll
    for (int i = 0; i < 4; i++) {
      const int row = row0 + tr * 4 + i;
      if (row < NN) {
        float4 o = make_float4(p[i][0] + c0, p[i][1] + c1, p[i][2] + c2, p[i][3] + c3);
        *(float4*)&filt[(size_t)row * 4] = o;
      }
    }
  }
}

__global__ void zero4_kernel(u32* __restrict__ maxv) {
  if (threadIdx.x < 4) maxv[threadIdx.x] = 0u;
}

__global__ __launch_bounds__(256) void maxv_kernel(const float* __restrict__ filt,
                                                   u32* __restrict__ maxv)
{
  __shared__ u32 lm[4];
  if (threadIdx.x < 4) lm[threadIdx.x] = 0u;
  __syncthreads();
  const int n = blockIdx.x * 256 + threadIdx.x;
  if (n < NN) {
    const float4 v = *(const float4*)&filt[(size_t)n * 4];
    atomicMax(&lm[0], encf(v.x));
    atomicMax(&lm[1], encf(v.y));
    atomicMax(&lm[2], encf(v.z));
    atomicMax(&lm[3], encf(v.w));
  }
  __syncthreads();
  if (threadIdx.x < 4) atomicMax(&maxv[threadIdx.x], lm[threadIdx.x]);
}

// ---------------- node sort keys: (enc(v), node), padded ----------------
__global__ __launch_bounds__(256) void nodeprep_kernel(const float* __restrict__ filt,
                                                       u64* __restrict__ nodekeys)
{
  const int n = blockIdx.x * 256 + threadIdx.x;
  const int f = blockIdx.y;
  if (n < NN) {
    const float v = filt[(size_t)n * 4 + f];
    nodekeys[(size_t)f * SEGN + n] = ((u64)encf(v) << 32) | (u32)n;
  } else if (n < SEGN) {
    nodekeys[(size_t)f * SEGN + n] = ~0ull;
  }
}

// ---------------- rank scatter ----------------
__global__ __launch_bounds__(256) void rank_kernel(const u64* __restrict__ nodekeys,
                                                   u32* __restrict__ rankOf,
                                                   u32* __restrict__ nodeOf)
{
  const int j = blockIdx.x * 256 + threadIdx.x;
  const int f = blockIdx.y;
  if (j < NN) {
    const u64 kk = nodekeys[(size_t)f * SEGN + j];
    const u32 node = (u32)(kk & 0xffffffffu);
    rankOf[(size_t)f * NN + node] = (u32)j;
    nodeOf[(size_t)f * SEGN + j] = node;
  }
}

// ---------------- births + essential deaths ----------------
__global__ __launch_bounds__(256) void init_kernel(
    const float* __restrict__ filt, const u32* __restrict__ maxv,
    float* __restrict__ out)
{
  const int n = blockIdx.x * 256 + threadIdx.x;
  const int f = blockIdx.y;
  if (n < NN) {
    const size_t idx = (size_t)f * NN + n;
    out[idx * 2 + 0] = filt[(size_t)n * 4 + f];
    out[idx * 2 + 1] = decf(maxv[f]);
  }
}

// ---------------- per-edge sort keys (padded) + rank-space endpoints ----------------
__global__ __launch_bounds__(256) void prep_kernel(
    const int* __restrict__ ei, const float* __restrict__ filt,
    const u32* __restrict__ rankOf,
    u32* __restrict__ erank, u64* __restrict__ skeys)
{
  const int e = blockIdx.x * 256 + threadIdx.x;
  if (e < NE) {
    const int s = ei[e];
    const int d = ei[NE + e];
    const float4 vs = *(const float4*)&filt[(size_t)s * 4];
    const float4 vd = *(const float4*)&filt[(size_t)d * 4];
    skeys[0 * (size_t)SEG + e] = ((u64)encf(fmaxf(vs.x, vd.x)) << 32) | (u32)e;
    skeys[1 * (size_t)SEG + e] = ((u64)encf(fmaxf(vs.y, vd.y)) << 32) | (u32)e;
    skeys[2 * (size_t)SEG + e] = ((u64)encf(fmaxf(vs.z, vd.z)) << 32) | (u32)e;
    skeys[3 * (size_t)SEG + e] = ((u64)encf(fmaxf(vs.w, vd.w)) << 32) | (u32)e;
    #pragma unroll
    for (int f = 0; f < 4; f++) {
      const u32 ru = rankOf[(size_t)f * NN + s];
      const u32 rt = rankOf[(size_t)f * NN + d];
      erank[(size_t)f * NE + e] = (ru << 16) | rt;
    }
  } else if (e < SEG) {
    skeys[0 * (size_t)SEG + e] = ~0ull; skeys[1 * (size_t)SEG + e] = ~0ull;
    skeys[2 * (size_t)SEG + e] = ~0ull; skeys[3 * (size_t)SEG + e] = ~0ull;
  }
}

// ---------------- bitonic: fused LDS phases k=2..4096 ----------------
__global__ __launch_bounds__(256) void bitonic_lds_full(u64* __restrict__ keys, int seglen)
{
  __shared__ u64 sh[4096];
  u64* a = keys + (size_t)blockIdx.y * seglen + (size_t)blockIdx.x * 4096;
  const int gbase = blockIdx.x * 4096;
  for (int i = threadIdx.x; i < 4096; i += 256) sh[i] = a[i];
  __syncthreads();
  for (int k = 2; k <= 4096; k <<= 1) {
    for (int j = k >> 1; j >= 1; j >>= 1) {
      for (int p = threadIdx.x; p < 2048; p += 256) {
        const int i = ((p & ~(j - 1)) << 1) | (p & (j - 1));
        const int ixj = i + j;
        const bool up = (((gbase + i) & k) == 0);
        const u64 x = sh[i], y = sh[ixj];
        if ((x > y) == up) { sh[i] = y; sh[ixj] = x; }
      }
      __syncthreads();
    }
  }
  for (int i = threadIdx.x; i < 4096; i += 256) a[i] = sh[i];
}

// ---------------- bitonic: fused LDS tail (fixed k, j=2048..1) ----------------
__global__ __launch_bounds__(256) void bitonic_lds_tail(u64* __restrict__ keys, int seglen, int k)
{
  __shared__ u64 sh[4096];
  u64* a = keys + (size_t)blockIdx.y * seglen + (size_t)blockIdx.x * 4096;
  const int gbase = blockIdx.x * 4096;
  for (int i = threadIdx.x; i < 4096; i += 256) sh[i] = a[i];
  __syncthreads();
  for (int j = 2048; j >= 1; j >>= 1) {
    for (int p = threadIdx.x; p < 2048; p += 256) {
      const int i = ((p & ~(j - 1)) << 1) | (p & (j - 1));
      const int ixj = i + j;
      const bool up = (((gbase + i) & k) == 0);
      const u64 x = sh[i], y = sh[ixj];
      if ((x > y) == up) { sh[i] = y; sh[ixj] = x; }
    }
    __syncthreads();
  }
  for (int i = threadIdx.x; i < 4096; i += 256) a[i] = sh[i];
}

// ---------------- bitonic: one global pass (j >= 4096) ----------------
__global__ __launch_bounds__(256) void bitonic_global(u64* __restrict__ keys, int seglen,
                                                      int k, int j)
{
  const int i = blockIdx.x * 256 + threadIdx.x;
  u64* a = keys + (size_t)blockIdx.y * seglen;
  const int ixj = i ^ j;
  if (ixj > i) {
    const u64 x = a[i], y = a[ixj];
    const bool up = ((i & k) == 0);
    if ((x > y) == up) { a[i] = y; a[ixj] = x; }
  }
}

// ---------------- prefix components at partition boundaries (per filtration) ----
__global__ __launch_bounds__(1024) void prefixcc_kernel(
    const u64* __restrict__ skeys, const u32* __restrict__ erank,
    u16* __restrict__ snap)
{
  __shared__ u16 lab[NN];      // 100 KB
  __shared__ u32 eL[PIECE];    // 50 KB
  __shared__ u32 chg;
  const int f = blockIdx.x;
  const int tid = threadIdx.x;
  const u64* ks = skeys + (size_t)f * SEG;
  const u32* er = erank + (size_t)f * NE;

  u32* lab32 = (u32*)lab;
  for (int j = tid; j < NN / 2; j += 1024)
    lab32[j] = ((u32)(2 * j + 1) << 16) | (u32)(2 * j);
  __syncthreads();

  for (int s = 1; s < NPART; s++) {
    const int lo = PB[s - 1], hi = PB[s];
    for (int plo = lo; plo < hi; plo += PIECE) {
      int phi = plo + PIECE; if (phi > hi) phi = hi;
      const int len = phi - plo;
      for (int i = tid; i < len; i += 1024)
        eL[i] = er[(u32)(ks[plo + i] & 0xffffffffu)];
      __syncthreads();
      for (int r = 0; r < CCMAXR; r++) {
        if (tid == 0) chg = 0u;
        __syncthreads();
        for (int i = tid; i < len; i += 1024) {
          const u32 pr = eL[i];
          const u32 la = lab[pr >> 16], lb = lab[pr & 0xffffu];
          if (la != lb) {
            const u32 h = la > lb ? la : lb;
            const u32 l2 = la ^ lb ^ h;
            if (l2 < (u32)lab[h]) { lab[h] = (u16)l2; chg = 1u; }
          }
        }
        for (int x = tid; x < NN; x += 1024) {
          const u32 l0 = lab[x];
          const u32 l1 = lab[l0];
          if (l1 != l0) { lab[x] = (u16)l1; chg = 1u; }
        }
        __syncthreads();
        if (chg == 0u) break;
        __syncthreads();
      }
    }
    u32* sn32 = (u32*)(snap + ((size_t)f * NPART + s) * NN);
    for (int j = tid; j < NN / 2; j += 1024) sn32[j] = lab32[j];
  }
}

// ---------------- rank-space Kruskal over all sorted edges, 16-way partitioned ----
__global__ __launch_bounds__(512) void uf_kernel(
    const u64* __restrict__ skeys, const u32* __restrict__ erank,
    const u32* __restrict__ nodeOf, const u16* __restrict__ snap,
    float* __restrict__ out)
{
  __shared__ __align__(16) u16 par[NN];   // 100 KB
  const int q = blockIdx.x;               // partition
  const int f = blockIdx.y;               // filtration
  const int tid = threadIdx.x;

  // all 8 waves: vectorized parent init / snapshot load
  if (q == 0) {
    u32* par32 = (u32*)par;
    for (int j = tid; j < NN / 2; j += 512)
      par32[j] = ((u32)(2 * j + 1) << 16) | (u32)(2 * j);
  } else {
    const uint4* sn = (const uint4*)(snap + ((size_t)f * NPART + q) * NN);
    uint4* p4 = (uint4*)par;
    for (int j = tid; j < NN / 8; j += 512) p4[j] = sn[j];   // NN*2/16 = 6250
  }
  __syncthreads();
  if (tid >= 64) return;   // wave 0 runs the scan
  const int lane = tid;

  const u64* ks = skeys + (size_t)f * SEG;
  const u32* er = erank + (size_t)f * NE;
  const u32* ndOf = nodeOf + (size_t)f * SEGN;
  float* outf = out + (size_t)f * NN * 2;
  const int lo = PB[q], hi = PB[q + 1];

  u64 key = ks[lo + lane];
  u32 pr;
  { const u32 e0 = (u32)(key & 0xffffffffu); pr = (e0 < (u32)NE) ? er[e0] : 0u; }

  for (int base = lo; base < hi; base += 64) {
    u64 nkey = ~0ull;
    if (base + 64 < hi) nkey = ks[base + 64 + lane];

    const bool live = (base + lane < hi);
    int u = 0, t = 0;
    if (live) { u = (int)(pr >> 16); t = (int)(pr & 0xffffu); }

    // dual interleaved path-halving find in LDS (snapshot before batch merges)
    int ru = u, rt = t;
    u32 pu = par[ru], pt = par[rt];
    while (pu != (u32)ru || pt != (u32)rt) {
      const u32 gu = par[pu];
      const u32 gt = par[pt];
      if (pu != (u32)ru) { par[ru] = (u16)gu; ru = (int)gu; }
      if (pt != (u32)rt) { par[rt] = (u16)gt; rt = (int)gt; }
      pu = par[ru]; pt = par[rt];
    }

    u32 npr = 0u;
    if (base + 64 < hi) {
      const u32 ne = (u32)(nkey & 0xffffffffu);
      if (ne < (u32)NE) npr = er[ne];
    }

    // in-order merge resolution. l is wave-uniform (ffs of ballot), so the
    // broadcast is v_readlane (VALU-speed), not ds_bpermute -- the loop-carried
    // chain is readlane + a few VALU ops (~50cy/merge vs ~340 with __shfl).
    u64 cand = __ballot(live && (ru != rt));
    u32 mp = ((u32)ru << 16) | (u32)rt;
    int myLose = -1;
    while (cand) {
      const int l = __ffsll((long long)cand) - 1;
      cand &= (cand - 1);
      const u32 ab = (u32)__builtin_amdgcn_readlane((int)mp, l);
      const u32 a = ab >> 16, b = ab & 0xffffu;
      if (a != b) {
        const u32 win = a < b ? a : b;
        const u32 lose = a ^ b ^ win;
        if (lane == l) { par[lose] = (u16)win; myLose = (int)lose; }
        const u32 h2 = mp >> 16, l2 = mp & 0xffffu;
        mp = ((h2 == lose ? win : h2) << 16) | (l2 == lose ? win : l2);
      }
    }

    // parallel epilogue: one vmcnt stall per batch, unique writer per slot
    if (myLose >= 0) {
      const u32 node = ndOf[myLose];
      outf[(size_t)node * 2 + 1] = decf((u32)(key >> 32));
    }

    asm volatile("s_waitcnt lgkmcnt(0)" ::: "memory");
    __builtin_amdgcn_sched_barrier(0);
    key = nkey; pr = npr;
  }
}

extern "C" void kernel_launch(void* const* d_in, const int* in_sizes, int n_in,
                              void* d_out, int out_size, void* d_ws, size_t ws_size,
                              hipStream_t stream)
{
  const float* X  = (const float*)d_in[0];
  const float* W1 = (const float*)d_in[1];
  const float* b1 = (const float*)d_in[2];
  const float* W2 = (const float*)d_in[3];
  const float* b2 = (const float*)d_in[4];
  const int*   EI = (const int*)d_in[5];   // int32 per harness contract
  float* out = (float*)d_out;

  char* w = (char*)d_ws;
  u64*  skeys  = (u64*)w;   w += (size_t)4 * SEG * sizeof(u64);          // 8,388,608
  u16*  snap   = (u16*)w;   w += (size_t)NPART * 4 * NN * sizeof(u16);   // 6,400,000
  u32*  erank  = (u32*)w;   w += (size_t)4 * NE * sizeof(u32);           // 3,200,000
  float* filt  = (float*)w; w += (size_t)NN * 4 * sizeof(float);         //   800,000
  u32*  rankOf = (u32*)w;   w += (size_t)4 * NN * sizeof(u32);           //   800,000
  u32*  nodeOf = (u32*)w;   w += (size_t)4 * SEGN * sizeof(u32);         // 1,048,576
  u32*  maxv   = (u32*)w;   w += 4 * sizeof(u32);

  // nodekeys aliases the snap region (nodekeys is dead before prefixcc writes snap)
  u64* nodekeys = (u64*)snap;   // 4*SEGN*8 = 2,097,152 <= 6,400,000

  const size_t need = (size_t)(w - (char*)d_ws);
  if (ws_size < need) return;

  const int nodeBlocks = (NN + 255) / 256;

  zero4_kernel<<<dim3(1), dim3(64), 0, stream>>>(maxv);
  mlp_kernel<<<dim3((NN + 63) / 64), dim3(256), 0, stream>>>(X, W1, b1, W2, b2, filt);
  maxv_kernel<<<dim3(nodeBlocks, 1), dim3(256), 0, stream>>>(filt, maxv);
  nodeprep_kernel<<<dim3(SEGN / 256, 4), dim3(256), 0, stream>>>(filt, nodekeys);

  // node sort (4 segments of SEGN): rank space
  bitonic_lds_full<<<dim3(SEGN / 4096, 4), dim3(256), 0, stream>>>(nodekeys, SEGN);
  for (int k = 8192; k <= SEGN; k <<= 1) {
    for (int j = k >> 1; j >= 4096; j >>= 1)
      bitonic_global<<<dim3(SEGN / 256, 4), dim3(256), 0, stream>>>(nodekeys, SEGN, k, j);
    bitonic_lds_tail<<<dim3(SEGN / 4096, 4), dim3(256), 0, stream>>>(nodekeys, SEGN, k);
  }

  rank_kernel<<<dim3(SEGN / 256, 4), dim3(256), 0, stream>>>(nodekeys, rankOf, nodeOf);
  init_kernel<<<dim3(nodeBlocks, 4), dim3(256), 0, stream>>>(filt, maxv, out);
  prep_kernel<<<dim3(SEG / 256, 1), dim3(256), 0, stream>>>(EI, filt, rankOf, erank, skeys);

  // edge sort (4 segments of SEG; ~0ull padding sorts to the end)
  bitonic_lds_full<<<dim3(SEG / 4096, 4), dim3(256), 0, stream>>>(skeys, SEG);
  for (int k = 8192; k <= SEG; k <<= 1) {
    for (int j = k >> 1; j >= 4096; j >>= 1)
      bitonic_global<<<dim3(SEG / 256, 4), dim3(256), 0, stream>>>(skeys, SEG, k, j);
    bitonic_lds_tail<<<dim3(SEG / 4096, 4), dim3(256), 0, stream>>>(skeys, SEG, k);
  }

  // prefix components at partition boundaries (writes snap; overwrites nodekeys alias)
  prefixcc_kernel<<<dim3(4), dim3(1024), 0, stream>>>(skeys, erank, snap);

  // partitioned serial scans: 16 cost-balanced partitions x 4 filtrations
  uf_kernel<<<dim3(NPART, 4), dim3(512), 0, stream>>>(skeys, erank, nodeOf, snap, out);
}